// Round 8
// baseline (1070.717 us; speedup 1.0000x reference)
//
#include <hip/hip_runtime.h>
#include <hip/hip_bf16.h>
#include <hip/hip_cooperative_groups.h>
#include <cstdint>

namespace cg = cooperative_groups;

// ---------------------------------------------------------------------------
// GraphRLAgent: 2-layer GAT (heads=2 then 1) + global mean pool + 2 heads.
// Round 8: 6 dispatches total.
//  - cooperative front-end kernel: zero + weight swizzle -> degree/counts ->
//    tile scan -> scan-add -> scatter (grid.sync between phases).
//  - pool+head fused via done-counter (last block computes outputs).
//  - gat_agg_h2 pass-2 unrolled to 8 edges in flight.
// ---------------------------------------------------------------------------

typedef __attribute__((ext_vector_type(8))) short bf16x8;
typedef __attribute__((ext_vector_type(4))) float f32x4;

__device__ __forceinline__ float wave_sum(float v) {
#pragma unroll
    for (int off = 32; off >= 1; off >>= 1) v += __shfl_xor(v, off, 64);
    return v;
}

__device__ __forceinline__ unsigned short f2bf(float f) {
    union { float f; uint32_t u; } c; c.f = f;
    uint32_t u = c.u;
    return (unsigned short)((u + 0x7fffu + ((u >> 16) & 1u)) >> 16);
}

__device__ __forceinline__ float bf2f(unsigned short u) {
    union { uint32_t u; float f; } c; c.u = ((uint32_t)u) << 16;
    return c.f;
}

// ------------------------- B swizzle body ---------------------------------

template <int K, int FOUT>
__device__ __forceinline__ void swizzle_body(const float* __restrict__ W,
                                             unsigned short* __restrict__ Bsw, int tid) {
    constexpr int CPW = FOUT / 4, NCT = CPW / 16, KST = K / 32;
    if (tid >= K * FOUT / 8) return;
    int lane = tid & 63;
    int rest = tid >> 6;
    int t = rest % KST; rest /= KST;
    int c = rest % NCT; rest /= NCT;
    int cg_ = rest;
    int quad = lane >> 4, lo = lane & 15;
    int col = cg_ * CPW + c * 16 + lo;
    unsigned short v[8];
#pragma unroll
    for (int j = 0; j < 8; ++j)
        v[j] = f2bf(W[(t * 32 + quad * 8 + j) * FOUT + col]);
    ushort4* dst = (ushort4*)(Bsw + (size_t)tid * 8);
    ushort4 o0, o1;
    o0.x = v[0]; o0.y = v[1]; o0.z = v[2]; o0.w = v[3];
    o1.x = v[4]; o1.y = v[5]; o1.z = v[6]; o1.w = v[7];
    dst[0] = o0; dst[1] = o1;
}

// ------------------------- cooperative front-end --------------------------
// phase0: zero workspace region + swizzle W1/W2 to frag order
// phase1: degree histogram + per-graph node counts
// phase2: per-1024-tile exclusive scan of deg (tile-local), tile sums
// phase3: scan tile sums in-wave, add offsets -> rowptr/cursor
// phase4: scatter csr_src by dst

__global__ __launch_bounds__(256, 4) void csr_build(
    const int* __restrict__ ei, const int* __restrict__ batch,
    const float* __restrict__ W1, const float* __restrict__ W2,
    unsigned short* __restrict__ B1, unsigned short* __restrict__ B2,
    int* __restrict__ zbase, int zn4,
    int* __restrict__ deg, int* __restrict__ cnt, int* __restrict__ tsum,
    int* __restrict__ rowptr, int* __restrict__ cursor, int* __restrict__ csrsrc,
    int E, int N, int T) {
    cg::grid_group grid = cg::this_grid();
    const int gt = blockIdx.x * 256 + threadIdx.x;
    const int GT = gridDim.x * 256;
    const int ET = E + N;
    __shared__ int sbuf[256];
    __shared__ int s_toff;

    // phase 0: zero + swizzle
    for (int i = gt; i < zn4; i += GT) ((int4*)zbase)[i] = make_int4(0, 0, 0, 0);
    if (gt < 4096)       swizzle_body<128, 256>(W1, B1, gt);
    else if (gt < 8192)  swizzle_body<256, 128>(W2, B2, gt - 4096);
    __threadfence();
    grid.sync();

    // phase 1: degree + graph counts
    for (int i = gt; i < ET; i += GT) {
        int dst = (i < E) ? ei[E + i] : (i - E);
        atomicAdd(&deg[dst], 1);
    }
    for (int i = gt; i < N; i += GT) atomicAdd(&cnt[batch[i]], 1);
    __threadfence();
    grid.sync();

    // phase 2: tile-local scan (blocks < T)
    if ((int)blockIdx.x < T) {
        const int t = threadIdx.x;
        const int base = blockIdx.x * 1024 + t * 4;
        int v[4]; int s = 0;
#pragma unroll
        for (int k = 0; k < 4; ++k) { v[k] = (base + k < N) ? deg[base + k] : 0; s += v[k]; }
        sbuf[t] = s;
        __syncthreads();
#pragma unroll
        for (int off = 1; off < 256; off <<= 1) {
            int x = (t >= off) ? sbuf[t - off] : 0;
            __syncthreads();
            sbuf[t] += x;
            __syncthreads();
        }
        int run = sbuf[t] - s;
#pragma unroll
        for (int k = 0; k < 4; ++k) {
            if (base + k < N) deg[base + k] = run;
            run += v[k];
        }
        if (t == 255) tsum[blockIdx.x] = sbuf[255];
    }
    __threadfence();
    grid.sync();

    // phase 3: add tile offsets (blocks < T); T <= 64
    if ((int)blockIdx.x < T) {
        const int tile = blockIdx.x;
        if (threadIdx.x < 64) {
            int t = threadIdx.x;
            int v = (t < T) ? tsum[t] : 0;
#pragma unroll
            for (int off = 1; off < 64; off <<= 1) {
                int x = __shfl_up(v, off, 64);
                if (t >= off) v += x;
            }
            int toff = (tile == 0) ? 0 : __shfl(v, tile - 1, 64);
            if (t == 0) s_toff = toff;
            if (tile == 0 && t == 63) rowptr[N] = v;
        }
        __syncthreads();
        const int toff = s_toff;
        int i = tile * 1024 + threadIdx.x * 4;
#pragma unroll
        for (int k = 0; k < 4; ++k) {
            if (i + k < N) {
                int r = deg[i + k] + toff;
                rowptr[i + k] = r;
                cursor[i + k] = r;
            }
        }
    }
    __threadfence();
    grid.sync();

    // phase 4: scatter
    for (int i = gt; i < ET; i += GT) {
        int src, dst;
        if (i < E) { src = ei[i]; dst = ei[E + i]; }
        else       { src = dst = i - E; }
        int pos = atomicAdd(&cursor[dst], 1);
        csrsrc[pos] = src;
    }
}

// ------------------------- bf16 MFMA GEMM + fused attn coef ---------------

template <int K, int FOUT, int H, bool A32>
__global__ __launch_bounds__(256) void gemm_mfma(const void* __restrict__ Av,
                                                 const unsigned short* __restrict__ Bsw,
                                                 const float* __restrict__ a_src,
                                                 const float* __restrict__ a_dst,
                                                 float* __restrict__ es, float* __restrict__ ed,
                                                 unsigned short* __restrict__ C, int N) {
    constexpr int CPW = FOUT / 4;
    constexpr int NCT = CPW / 16;
    constexpr int KST = K / 32;
    const int tid = threadIdx.x;
    const int wave = tid >> 6, lane = tid & 63;
    const int quad = lane >> 4, lo = lane & 15;
    const int n0 = blockIdx.x * 64;
    const int c0 = wave * CPW;

    bf16x8 bf[NCT][KST];
    {
        const bf16x8* Bp = (const bf16x8*)Bsw;
#pragma unroll
        for (int c = 0; c < NCT; ++c)
#pragma unroll
            for (int t = 0; t < KST; ++t)
                bf[c][t] = Bp[((wave * NCT + c) * KST + t) * 64 + lane];
    }

    f32x4 acc[4][NCT];
#pragma unroll
    for (int r = 0; r < 4; ++r)
#pragma unroll
        for (int c = 0; c < NCT; ++c) acc[r][c] = (f32x4){0.f, 0.f, 0.f, 0.f};

#pragma unroll
    for (int r = 0; r < 4; ++r) {
        const int arow = n0 + r * 16 + lo;
        if (A32) {
            const size_t rclamp = (arow < N) ? (size_t)arow : 0;
            const float* Ar = (const float*)Av + rclamp * K + quad * 8;
            const bool valid = arow < N;
#pragma unroll
            for (int t = 0; t < KST; ++t) {
                bf16x8 af;
                if (valid) {
                    float4 v0 = *(const float4*)(Ar + t * 32);
                    float4 v1 = *(const float4*)(Ar + t * 32 + 4);
                    af[0] = (short)f2bf(v0.x); af[1] = (short)f2bf(v0.y);
                    af[2] = (short)f2bf(v0.z); af[3] = (short)f2bf(v0.w);
                    af[4] = (short)f2bf(v1.x); af[5] = (short)f2bf(v1.y);
                    af[6] = (short)f2bf(v1.z); af[7] = (short)f2bf(v1.w);
                } else {
                    af = (bf16x8){0, 0, 0, 0, 0, 0, 0, 0};
                }
#pragma unroll
                for (int c = 0; c < NCT; ++c)
                    acc[r][c] = __builtin_amdgcn_mfma_f32_16x16x32_bf16(af, bf[c][t], acc[r][c],
                                                                       0, 0, 0);
            }
        } else {
            const unsigned short* Ar = (const unsigned short*)Av + (size_t)arow * K + quad * 8;
#pragma unroll
            for (int t = 0; t < KST; ++t) {
                bf16x8 af = *(const bf16x8*)(Ar + t * 32);
#pragma unroll
                for (int c = 0; c < NCT; ++c)
                    acc[r][c] = __builtin_amdgcn_mfma_f32_16x16x32_bf16(af, bf[c][t], acc[r][c],
                                                                       0, 0, 0);
            }
        }
    }

    // C/D layout: col = lane&15, row = quad*4 + j
#pragma unroll
    for (int r = 0; r < 4; ++r) {
        int row = n0 + r * 16 + quad * 4;
#pragma unroll
        for (int c = 0; c < NCT; ++c) {
            int col = c0 + c * 16 + lo;
#pragma unroll
            for (int j = 0; j < 4; ++j)
                if (row + j < N) C[(size_t)(row + j) * FOUT + col] = f2bf(acc[r][c][j]);
        }
    }

    // fused attention coefficients
    float asv[NCT], adv[NCT];
#pragma unroll
    for (int c = 0; c < NCT; ++c) {
        int col = c0 + c * 16 + lo;
        asv[c] = a_src[col];
        adv[c] = a_dst[col];
    }
    const int h = c0 / (FOUT / H);
#pragma unroll
    for (int r = 0; r < 4; ++r) {
#pragma unroll
        for (int j = 0; j < 4; ++j) {
            float ps = 0.f, pd = 0.f;
#pragma unroll
            for (int c = 0; c < NCT; ++c) { ps += acc[r][c][j] * asv[c]; pd += acc[r][c][j] * adv[c]; }
#pragma unroll
            for (int off = 1; off <= 8; off <<= 1) {
                ps += __shfl_xor(ps, off, 64);
                pd += __shfl_xor(pd, off, 64);
            }
            int row = n0 + r * 16 + quad * 4 + j;
            if (lo == 0 && row < N) {
                atomicAdd(&es[row * H + h], ps);
                atomicAdd(&ed[row * H + h], pd);
            }
        }
    }
}

// ------------------------- GAT aggregation, H=2 (fused softmax) -----------

__global__ void gat_agg_h2(const unsigned short* __restrict__ Hpre,
                           const float* __restrict__ es, const float* __restrict__ ed,
                           float* __restrict__ w,
                           const int* __restrict__ rowptr, const int* __restrict__ csr_src,
                           const float* __restrict__ bias, unsigned short* __restrict__ out,
                           int N) {
    int wid = (blockIdx.x * blockDim.x + threadIdx.x) >> 6;
    int lane = threadIdx.x & 63;
    if (wid >= N) return;
    const int rs = rowptr[wid], re = rowptr[wid + 1];
    const int h = lane >> 5;
    const float edn = ed[wid * 2 + h];

    float z = 0.f;
    for (int i = rs + (lane & 31); i < re; i += 32) {
        int s = csr_src[i];
        float e = es[s * 2 + h] + edn;
        e = (e > 0.f) ? e : 0.2f * e;
        float ww = __expf(e);
        z += ww;
        w[i * 2 + h] = ww;
    }
#pragma unroll
    for (int off = 16; off >= 1; off >>= 1) z += __shfl_xor(z, off, 64);
    const float rz = 1.f / (z + 1e-16f);
    __threadfence_block();  // drain vmcnt: same-wave RAW on w

    float4 a0 = {0.f, 0.f, 0.f, 0.f}, a1 = {0.f, 0.f, 0.f, 0.f};
    float4 a2 = {0.f, 0.f, 0.f, 0.f}, a3 = {0.f, 0.f, 0.f, 0.f};
    int i = rs;
    for (; i + 8 <= re; i += 8) {
        int s[8]; float wk[8]; ushort4 u[8];
#pragma unroll
        for (int k = 0; k < 8; ++k) s[k] = csr_src[i + k];
#pragma unroll
        for (int k = 0; k < 8; ++k) wk[k] = w[(i + k) * 2 + h];
#pragma unroll
        for (int k = 0; k < 8; ++k)
            u[k] = *(const ushort4*)(Hpre + (size_t)s[k] * 256 + lane * 4);
#pragma unroll
        for (int k = 0; k < 8; ++k) {
            float4* a = (k & 3) == 0 ? &a0 : (k & 3) == 1 ? &a1 : (k & 3) == 2 ? &a2 : &a3;
            a->x += wk[k] * bf2f(u[k].x); a->y += wk[k] * bf2f(u[k].y);
            a->z += wk[k] * bf2f(u[k].z); a->w += wk[k] * bf2f(u[k].w);
        }
    }
    for (; i < re; ++i) {
        int s0 = csr_src[i];
        float w0 = w[i * 2 + h];
        ushort4 u0 = *(const ushort4*)(Hpre + (size_t)s0 * 256 + lane * 4);
        a0.x += w0 * bf2f(u0.x); a0.y += w0 * bf2f(u0.y);
        a0.z += w0 * bf2f(u0.z); a0.w += w0 * bf2f(u0.w);
    }
    float4 bv = ((const float4*)bias)[lane];
    float ox = (a0.x + a1.x + a2.x + a3.x) * rz + bv.x;
    float oy = (a0.y + a1.y + a2.y + a3.y) * rz + bv.y;
    float oz = (a0.z + a1.z + a2.z + a3.z) * rz + bv.z;
    float ow = (a0.w + a1.w + a2.w + a3.w) * rz + bv.w;
    ox = (ox > 0.f) ? ox : __expf(ox) - 1.f;
    oy = (oy > 0.f) ? oy : __expf(oy) - 1.f;
    oz = (oz > 0.f) ? oz : __expf(oz) - 1.f;
    ow = (ow > 0.f) ? ow : __expf(ow) - 1.f;
    ushort4 o;
    o.x = f2bf(ox); o.y = f2bf(oy); o.z = f2bf(oz); o.w = f2bf(ow);
    *(ushort4*)(out + (size_t)wid * 256 + lane * 4) = o;
}

// ------------------------- GAT aggregation, H=1 (fused softmax) -----------

__global__ void gat_agg_h1(const unsigned short* __restrict__ Hpre,
                           const float* __restrict__ es, const float* __restrict__ ed,
                           float* __restrict__ w,
                           const int* __restrict__ rowptr, const int* __restrict__ csr_src,
                           const float* __restrict__ bias, unsigned short* __restrict__ out,
                           int N) {
    int wid = (blockIdx.x * blockDim.x + threadIdx.x) >> 6;
    int lane = threadIdx.x & 63;
    if (wid >= N) return;
    const int rs = rowptr[wid], re = rowptr[wid + 1];
    const int half = lane >> 5, c = lane & 31;
    const float edn = ed[wid];

    float z = 0.f;
    for (int i = rs + lane; i < re; i += 64) {
        int s = csr_src[i];
        float e = es[s] + edn;
        e = (e > 0.f) ? e : 0.2f * e;
        float ww = __expf(e);
        z += ww;
        w[i] = ww;
    }
    z = wave_sum(z);
    const float rz = 1.f / (z + 1e-16f);
    __threadfence_block();  // drain vmcnt: same-wave RAW on w

    float4 a0 = {0.f, 0.f, 0.f, 0.f}, a1 = {0.f, 0.f, 0.f, 0.f};
    float4 a2 = {0.f, 0.f, 0.f, 0.f}, a3 = {0.f, 0.f, 0.f, 0.f};
    int i = rs + half;
    for (; i + 6 < re; i += 8) {
        int s0 = csr_src[i], s1 = csr_src[i + 2], s2 = csr_src[i + 4], s3 = csr_src[i + 6];
        float w0 = w[i], w1 = w[i + 2], w2 = w[i + 4], w3 = w[i + 6];
        ushort4 u0 = *(const ushort4*)(Hpre + (size_t)s0 * 128 + c * 4);
        ushort4 u1 = *(const ushort4*)(Hpre + (size_t)s1 * 128 + c * 4);
        ushort4 u2 = *(const ushort4*)(Hpre + (size_t)s2 * 128 + c * 4);
        ushort4 u3 = *(const ushort4*)(Hpre + (size_t)s3 * 128 + c * 4);
        a0.x += w0 * bf2f(u0.x); a0.y += w0 * bf2f(u0.y);
        a0.z += w0 * bf2f(u0.z); a0.w += w0 * bf2f(u0.w);
        a1.x += w1 * bf2f(u1.x); a1.y += w1 * bf2f(u1.y);
        a1.z += w1 * bf2f(u1.z); a1.w += w1 * bf2f(u1.w);
        a2.x += w2 * bf2f(u2.x); a2.y += w2 * bf2f(u2.y);
        a2.z += w2 * bf2f(u2.z); a2.w += w2 * bf2f(u2.w);
        a3.x += w3 * bf2f(u3.x); a3.y += w3 * bf2f(u3.y);
        a3.z += w3 * bf2f(u3.z); a3.w += w3 * bf2f(u3.w);
    }
    for (; i < re; i += 2) {
        int s0 = csr_src[i];
        float w0 = w[i];
        ushort4 u0 = *(const ushort4*)(Hpre + (size_t)s0 * 128 + c * 4);
        a0.x += w0 * bf2f(u0.x); a0.y += w0 * bf2f(u0.y);
        a0.z += w0 * bf2f(u0.z); a0.w += w0 * bf2f(u0.w);
    }
    float ox = a0.x + a1.x + a2.x + a3.x;
    float oy = a0.y + a1.y + a2.y + a3.y;
    float oz = a0.z + a1.z + a2.z + a3.z;
    float ow = a0.w + a1.w + a2.w + a3.w;
    ox += __shfl_xor(ox, 32, 64);
    oy += __shfl_xor(oy, 32, 64);
    oz += __shfl_xor(oz, 32, 64);
    ow += __shfl_xor(ow, 32, 64);
    if (lane < 32) {
        float4 bv = ((const float4*)bias)[c];
        ox = ox * rz + bv.x; oy = oy * rz + bv.y; oz = oz * rz + bv.z; ow = ow * rz + bv.w;
        ox = (ox > 0.f) ? ox : __expf(ox) - 1.f;
        oy = (oy > 0.f) ? oy : __expf(oy) - 1.f;
        oz = (oz > 0.f) ? oz : __expf(oz) - 1.f;
        ow = (ow > 0.f) ? ow : __expf(ow) - 1.f;
        ushort4 o;
        o.x = f2bf(ox); o.y = f2bf(oy); o.z = f2bf(oz); o.w = f2bf(ow);
        *(ushort4*)(out + (size_t)wid * 128 + c * 4) = o;
    }
}

// ------------------------- pool + heads (fused, done-counter) -------------

#define PCHUNK 256

__global__ __launch_bounds__(256) void pool_head(const unsigned short* __restrict__ h2,
                                                 const int* __restrict__ batch,
                                                 float* __restrict__ xsum,
                                                 const int* __restrict__ cnt,
                                                 int* __restrict__ done,
                                                 const float* __restrict__ Wp,
                                                 const float* __restrict__ bp,
                                                 const float* __restrict__ Wv,
                                                 const float* __restrict__ bv,
                                                 float* __restrict__ out, int N, int PB) {
    const int base = blockIdx.x * PCHUNK;
    const int rg = threadIdx.x >> 6;
    const int c2 = threadIdx.x & 63;
    float ax = 0.f, ay = 0.f;
    int gcur = -1;
    for (int r = rg; r < PCHUNK; r += 4) {
        int i = base + r;
        if (i >= N) break;
        int g = batch[i];
        if (g != gcur) {
            if (gcur >= 0) {
                atomicAdd(&xsum[gcur * 128 + c2 * 2 + 0], ax);
                atomicAdd(&xsum[gcur * 128 + c2 * 2 + 1], ay);
            }
            gcur = g; ax = 0.f; ay = 0.f;
        }
        ushort2 u = *(const ushort2*)(h2 + (size_t)i * 128 + c2 * 2);
        ax += bf2f(u.x); ay += bf2f(u.y);
    }
    if (gcur >= 0) {
        atomicAdd(&xsum[gcur * 128 + c2 * 2 + 0], ax);
        atomicAdd(&xsum[gcur * 128 + c2 * 2 + 1], ay);
    }

    // last block computes the heads
    __threadfence();
    __syncthreads();
    __shared__ int s_last;
    if (threadIdx.x == 0) s_last = (atomicAdd(done, 1) == PB - 1) ? 1 : 0;
    __syncthreads();
    if (!s_last) return;
    __threadfence();

    for (int o = threadIdx.x; o < 64 * 32; o += 256) {
        int g = o >> 5, a = o & 31;
        float inv = 1.f / fmaxf((float)cnt[g], 1.f);
        float acc = 0.f;
        for (int k = 0; k < 128; ++k) acc += xsum[g * 128 + k] * Wp[k * 32 + a];
        out[g * 32 + a] = acc * inv + bp[a];
    }
    if (threadIdx.x < 64) {
        int g = threadIdx.x;
        float inv = 1.f / fmaxf((float)cnt[g], 1.f);
        float acc = 0.f;
        for (int k = 0; k < 128; ++k) acc += xsum[g * 128 + k] * Wv[k];
        out[64 * 32 + g] = acc * inv + bv[0];
    }
}

// ---------------------------------------------------------------------------

extern "C" void kernel_launch(void* const* d_in, const int* in_sizes, int n_in,
                              void* d_out, int out_size, void* d_ws, size_t ws_size,
                              hipStream_t stream) {
    const float* x      = (const float*)d_in[0];
    const int*   ei     = (const int*)d_in[1];
    const int*   batch  = (const int*)d_in[2];
    const float* W1     = (const float*)d_in[3];
    const float* a_src1 = (const float*)d_in[4];
    const float* a_dst1 = (const float*)d_in[5];
    const float* b1     = (const float*)d_in[6];
    const float* W2     = (const float*)d_in[7];
    const float* a_src2 = (const float*)d_in[8];
    const float* a_dst2 = (const float*)d_in[9];
    const float* b2     = (const float*)d_in[10];
    const float* Wp     = (const float*)d_in[11];
    const float* bp     = (const float*)d_in[12];
    const float* Wv     = (const float*)d_in[13];
    const float* bv     = (const float*)d_in[14];

    const int N  = in_sizes[0] / 128;
    const int E  = in_sizes[1] / 2;
    const int ET = E + N;
    const int TILES = (N + 1023) / 1024;
    const int NPAD = ((N + 63) / 64) * 64;
    const int NBLK = NPAD / 64;
    const int PBLK = (N + PCHUNK - 1) / PCHUNK;

    char* ws = (char*)d_ws;
    size_t off = 0;
    auto alloc = [&](size_t bytes) -> void* {
        void* p = ws + off;
        off = (off + bytes + 255) & ~(size_t)255;
        return p;
    };
    unsigned short* h1pre = (unsigned short*)alloc((size_t)NPAD * 256 * 2);  // reused as h2pre
    unsigned short* h1bf  = (unsigned short*)alloc((size_t)NPAD * 256 * 2);
    unsigned short* h2bf  = (unsigned short*)alloc((size_t)N * 128 * 2);
    unsigned short* w1sw  = (unsigned short*)alloc((size_t)128 * 256 * 2);
    unsigned short* w2sw  = (unsigned short*)alloc((size_t)256 * 128 * 2);
    float* wbuf   = (float*)alloc((size_t)ET * 2 * 4);
    // contiguous zero region: deg | es1 | ed1 | es2 | ed2 | xsum | cnt | done
    const int ZINTS = 7 * N + 64 * 128 + 64 + 1;
    int*   zbase  = (int*)alloc(((size_t)ZINTS + 8) * 4);
    int*   deg    = zbase;
    float* es1    = (float*)(zbase + N);
    float* ed1    = es1 + 2 * N;
    float* es2    = ed1 + 2 * N;
    float* ed2    = es2 + N;
    float* xsum   = ed2 + N;
    int*   cnt    = (int*)(xsum + 64 * 128);
    int*   done   = cnt + 64;
    int*   rowptr = (int*)alloc((size_t)(N + 1) * 4);
    int*   cursor = (int*)alloc((size_t)N * 4);
    int*   csrsrc = (int*)alloc((size_t)ET * 4);
    int*   tsum   = (int*)alloc(64 * 4);
    unsigned short* h2pre = h1pre;  // h1pre dead after layer-1 agg
    const int zn4 = (ZINTS + 3) / 4;

    // --- cooperative front-end: zero+swizzle / degree+cnt / scan / scatter ---
    {
        dim3 grid(832), block(256);
        int E_ = E, N_ = N, T_ = TILES, zn4_ = zn4;
        void* args[] = {(void*)&ei, (void*)&batch, (void*)&W1, (void*)&W2,
                        (void*)&w1sw, (void*)&w2sw, (void*)&zbase, (void*)&zn4_,
                        (void*)&deg, (void*)&cnt, (void*)&tsum,
                        (void*)&rowptr, (void*)&cursor, (void*)&csrsrc,
                        (void*)&E_, (void*)&N_, (void*)&T_};
        hipLaunchCooperativeKernel((void*)csr_build, grid, block, args, 0, stream);
    }

    // --- layer 1: heads=2 (A = fp32 x, cast in-reg; es1/ed1 fused) ---
    gemm_mfma<128, 256, 2, true><<<NBLK, 256, 0, stream>>>(x, w1sw, a_src1, a_dst1,
                                                           es1, ed1, h1pre, N);
    gat_agg_h2<<<(N + 3) / 4, 256, 0, stream>>>(h1pre, es1, ed1, wbuf, rowptr, csrsrc, b1,
                                                h1bf, N);

    // --- layer 2: heads=1 (es2/ed2 fused) ---
    gemm_mfma<256, 128, 1, false><<<NBLK, 256, 0, stream>>>(h1bf, w2sw, a_src2, a_dst2,
                                                            es2, ed2, h2pre, N);
    gat_agg_h1<<<(N + 3) / 4, 256, 0, stream>>>(h2pre, es2, ed2, wbuf, rowptr, csrsrc, b2,
                                                h2bf, N);

    // --- pool + heads (fused) ---
    pool_head<<<PBLK, 256, 0, stream>>>(h2bf, batch, xsum, cnt, done, Wp, bp, Wv, bv,
                                        (float*)d_out, N, PBLK);
}

// Round 9
// 604.203 us; speedup vs baseline: 1.7721x; 1.7721x over previous
//
#include <hip/hip_runtime.h>
#include <hip/hip_bf16.h>
#include <cstdint>

// ---------------------------------------------------------------------------
// GraphRLAgent: 2-layer GAT (heads=2 then 1) + global mean pool + 2 heads.
// Round 9: REVERT cooperative front-end (grid.sync ~180us/barrier on MI355X —
// 4 barriers cost 740us). Back to separate launches; KEEP pool+head fusion
// (done-counter) and the 8-deep gat_agg_h2 gather unroll. 11 dispatches.
// ---------------------------------------------------------------------------

typedef __attribute__((ext_vector_type(8))) short bf16x8;
typedef __attribute__((ext_vector_type(4))) float f32x4;

__device__ __forceinline__ float wave_sum(float v) {
#pragma unroll
    for (int off = 32; off >= 1; off >>= 1) v += __shfl_xor(v, off, 64);
    return v;
}

__device__ __forceinline__ unsigned short f2bf(float f) {
    union { float f; uint32_t u; } c; c.f = f;
    uint32_t u = c.u;
    return (unsigned short)((u + 0x7fffu + ((u >> 16) & 1u)) >> 16);
}

__device__ __forceinline__ float bf2f(unsigned short u) {
    union { uint32_t u; float f; } c; c.u = ((uint32_t)u) << 16;
    return c.f;
}

// ------------------------- zero (int4) ------------------------------------

__global__ void zero4_kernel(int* __restrict__ p, int n4) {
    int i = blockIdx.x * blockDim.x + threadIdx.x;
    if (i < n4) ((int4*)p)[i] = make_int4(0, 0, 0, 0);
}

// ------------------------- CSR construction -------------------------------
// self-loop lanes also accumulate per-graph node counts (for the mean pool).

__global__ void degree_kernel(const int* __restrict__ ei, const int* __restrict__ batch,
                              int* __restrict__ deg, int* __restrict__ cnt, int E, int N) {
    int i = blockIdx.x * blockDim.x + threadIdx.x;
    if (i >= E + N) return;
    if (i < E) {
        atomicAdd(&deg[ei[E + i]], 1);
    } else {
        int node = i - E;
        atomicAdd(&deg[node], 1);
        atomicAdd(&cnt[batch[node]], 1);
    }
}

__global__ __launch_bounds__(256) void scan_tiles(int* __restrict__ deg,
                                                  int* __restrict__ tsum, int N) {
    __shared__ int buf[256];
    const int t = threadIdx.x;
    const int base = blockIdx.x * 1024 + t * 4;
    int v[4]; int s = 0;
#pragma unroll
    for (int k = 0; k < 4; ++k) { v[k] = (base + k < N) ? deg[base + k] : 0; s += v[k]; }
    buf[t] = s;
    __syncthreads();
#pragma unroll
    for (int off = 1; off < 256; off <<= 1) {
        int x = (t >= off) ? buf[t - off] : 0;
        __syncthreads();
        buf[t] += x;
        __syncthreads();
    }
    int run = buf[t] - s;
#pragma unroll
    for (int k = 0; k < 4; ++k) {
        if (base + k < N) deg[base + k] = run;
        run += v[k];
    }
    if (t == 255) tsum[blockIdx.x] = buf[255];
}

// one block per 1024-node tile; re-scans the <=64 tile sums in-wave, then adds
// the tile offset to the tile-local prefixes.
__global__ __launch_bounds__(256) void scan_add(const int* __restrict__ partial,
                                                const int* __restrict__ tsum,
                                                int* __restrict__ rowptr,
                                                int* __restrict__ cursor, int N, int T) {
    __shared__ int s_toff;
    const int tile = blockIdx.x;
    if (threadIdx.x < 64) {
        int t = threadIdx.x;
        int v = (t < T) ? tsum[t] : 0;
#pragma unroll
        for (int off = 1; off < 64; off <<= 1) {
            int x = __shfl_up(v, off, 64);
            if (t >= off) v += x;
        }
        int toff = (tile == 0) ? 0 : __shfl(v, tile - 1, 64);
        if (t == 0) s_toff = toff;
        if (tile == 0 && t == 63) rowptr[N] = v;
    }
    __syncthreads();
    const int toff = s_toff;
    int i = tile * 1024 + threadIdx.x * 4;
#pragma unroll
    for (int k = 0; k < 4; ++k) {
        if (i + k < N) {
            int r = partial[i + k] + toff;
            rowptr[i + k] = r;
            cursor[i + k] = r;
        }
    }
}

__global__ void scatter_kernel(const int* __restrict__ ei, int* __restrict__ cursor,
                               int* __restrict__ csr_src, int E, int N) {
    int i = blockIdx.x * blockDim.x + threadIdx.x;
    if (i >= E + N) return;
    int src, dst;
    if (i < E) { src = ei[i]; dst = ei[E + i]; }
    else       { src = dst = i - E; }
    int pos = atomicAdd(&cursor[dst], 1);
    csr_src[pos] = src;
}

// ------------------------- B swizzle (fp32 W -> frag-ordered bf16) --------

template <int K, int FOUT>
__device__ __forceinline__ void swizzle_body(const float* __restrict__ W,
                                             unsigned short* __restrict__ Bsw, int tid) {
    constexpr int CPW = FOUT / 4, NCT = CPW / 16, KST = K / 32;
    if (tid >= K * FOUT / 8) return;
    int lane = tid & 63;
    int rest = tid >> 6;
    int t = rest % KST; rest /= KST;
    int c = rest % NCT; rest /= NCT;
    int cg_ = rest;
    int quad = lane >> 4, lo = lane & 15;
    int col = cg_ * CPW + c * 16 + lo;
    unsigned short v[8];
#pragma unroll
    for (int j = 0; j < 8; ++j)
        v[j] = f2bf(W[(t * 32 + quad * 8 + j) * FOUT + col]);
    ushort4* dst = (ushort4*)(Bsw + (size_t)tid * 8);
    ushort4 o0, o1;
    o0.x = v[0]; o0.y = v[1]; o0.z = v[2]; o0.w = v[3];
    o1.x = v[4]; o1.y = v[5]; o1.z = v[6]; o1.w = v[7];
    dst[0] = o0; dst[1] = o1;
}

__global__ void swizzle_both(const float* __restrict__ W1, const float* __restrict__ W2,
                             unsigned short* __restrict__ B1, unsigned short* __restrict__ B2) {
    int b = blockIdx.x;
    if (b < 16) swizzle_body<128, 256>(W1, B1, b * 256 + threadIdx.x);
    else        swizzle_body<256, 128>(W2, B2, (b - 16) * 256 + threadIdx.x);
}

// ------------------------- bf16 MFMA GEMM + fused attn coef ---------------

template <int K, int FOUT, int H, bool A32>
__global__ __launch_bounds__(256) void gemm_mfma(const void* __restrict__ Av,
                                                 const unsigned short* __restrict__ Bsw,
                                                 const float* __restrict__ a_src,
                                                 const float* __restrict__ a_dst,
                                                 float* __restrict__ es, float* __restrict__ ed,
                                                 unsigned short* __restrict__ C, int N) {
    constexpr int CPW = FOUT / 4;
    constexpr int NCT = CPW / 16;
    constexpr int KST = K / 32;
    const int tid = threadIdx.x;
    const int wave = tid >> 6, lane = tid & 63;
    const int quad = lane >> 4, lo = lane & 15;
    const int n0 = blockIdx.x * 64;
    const int c0 = wave * CPW;

    bf16x8 bf[NCT][KST];
    {
        const bf16x8* Bp = (const bf16x8*)Bsw;
#pragma unroll
        for (int c = 0; c < NCT; ++c)
#pragma unroll
            for (int t = 0; t < KST; ++t)
                bf[c][t] = Bp[((wave * NCT + c) * KST + t) * 64 + lane];
    }

    f32x4 acc[4][NCT];
#pragma unroll
    for (int r = 0; r < 4; ++r)
#pragma unroll
        for (int c = 0; c < NCT; ++c) acc[r][c] = (f32x4){0.f, 0.f, 0.f, 0.f};

#pragma unroll
    for (int r = 0; r < 4; ++r) {
        const int arow = n0 + r * 16 + lo;
        if (A32) {
            const size_t rclamp = (arow < N) ? (size_t)arow : 0;
            const float* Ar = (const float*)Av + rclamp * K + quad * 8;
            const bool valid = arow < N;
#pragma unroll
            for (int t = 0; t < KST; ++t) {
                bf16x8 af;
                if (valid) {
                    float4 v0 = *(const float4*)(Ar + t * 32);
                    float4 v1 = *(const float4*)(Ar + t * 32 + 4);
                    af[0] = (short)f2bf(v0.x); af[1] = (short)f2bf(v0.y);
                    af[2] = (short)f2bf(v0.z); af[3] = (short)f2bf(v0.w);
                    af[4] = (short)f2bf(v1.x); af[5] = (short)f2bf(v1.y);
                    af[6] = (short)f2bf(v1.z); af[7] = (short)f2bf(v1.w);
                } else {
                    af = (bf16x8){0, 0, 0, 0, 0, 0, 0, 0};
                }
#pragma unroll
                for (int c = 0; c < NCT; ++c)
                    acc[r][c] = __builtin_amdgcn_mfma_f32_16x16x32_bf16(af, bf[c][t], acc[r][c],
                                                                       0, 0, 0);
            }
        } else {
            const unsigned short* Ar = (const unsigned short*)Av + (size_t)arow * K + quad * 8;
#pragma unroll
            for (int t = 0; t < KST; ++t) {
                bf16x8 af = *(const bf16x8*)(Ar + t * 32);
#pragma unroll
                for (int c = 0; c < NCT; ++c)
                    acc[r][c] = __builtin_amdgcn_mfma_f32_16x16x32_bf16(af, bf[c][t], acc[r][c],
                                                                       0, 0, 0);
            }
        }
    }

    // C/D layout: col = lane&15, row = quad*4 + j
#pragma unroll
    for (int r = 0; r < 4; ++r) {
        int row = n0 + r * 16 + quad * 4;
#pragma unroll
        for (int c = 0; c < NCT; ++c) {
            int col = c0 + c * 16 + lo;
#pragma unroll
            for (int j = 0; j < 4; ++j)
                if (row + j < N) C[(size_t)(row + j) * FOUT + col] = f2bf(acc[r][c][j]);
        }
    }

    // fused attention coefficients
    float asv[NCT], adv[NCT];
#pragma unroll
    for (int c = 0; c < NCT; ++c) {
        int col = c0 + c * 16 + lo;
        asv[c] = a_src[col];
        adv[c] = a_dst[col];
    }
    const int h = c0 / (FOUT / H);
#pragma unroll
    for (int r = 0; r < 4; ++r) {
#pragma unroll
        for (int j = 0; j < 4; ++j) {
            float ps = 0.f, pd = 0.f;
#pragma unroll
            for (int c = 0; c < NCT; ++c) { ps += acc[r][c][j] * asv[c]; pd += acc[r][c][j] * adv[c]; }
#pragma unroll
            for (int off = 1; off <= 8; off <<= 1) {
                ps += __shfl_xor(ps, off, 64);
                pd += __shfl_xor(pd, off, 64);
            }
            int row = n0 + r * 16 + quad * 4 + j;
            if (lo == 0 && row < N) {
                atomicAdd(&es[row * H + h], ps);
                atomicAdd(&ed[row * H + h], pd);
            }
        }
    }
}

// ------------------------- GAT aggregation, H=2 (fused softmax) -----------

__global__ void gat_agg_h2(const unsigned short* __restrict__ Hpre,
                           const float* __restrict__ es, const float* __restrict__ ed,
                           float* __restrict__ w,
                           const int* __restrict__ rowptr, const int* __restrict__ csr_src,
                           const float* __restrict__ bias, unsigned short* __restrict__ out,
                           int N) {
    int wid = (blockIdx.x * blockDim.x + threadIdx.x) >> 6;
    int lane = threadIdx.x & 63;
    if (wid >= N) return;
    const int rs = rowptr[wid], re = rowptr[wid + 1];
    const int h = lane >> 5;
    const float edn = ed[wid * 2 + h];

    float z = 0.f;
    for (int i = rs + (lane & 31); i < re; i += 32) {
        int s = csr_src[i];
        float e = es[s * 2 + h] + edn;
        e = (e > 0.f) ? e : 0.2f * e;
        float ww = __expf(e);
        z += ww;
        w[i * 2 + h] = ww;
    }
#pragma unroll
    for (int off = 16; off >= 1; off >>= 1) z += __shfl_xor(z, off, 64);
    const float rz = 1.f / (z + 1e-16f);
    __threadfence_block();  // drain vmcnt: same-wave RAW on w

    float4 a0 = {0.f, 0.f, 0.f, 0.f}, a1 = {0.f, 0.f, 0.f, 0.f};
    float4 a2 = {0.f, 0.f, 0.f, 0.f}, a3 = {0.f, 0.f, 0.f, 0.f};
    int i = rs;
    for (; i + 8 <= re; i += 8) {
        int s[8]; float wk[8]; ushort4 u[8];
#pragma unroll
        for (int k = 0; k < 8; ++k) s[k] = csr_src[i + k];
#pragma unroll
        for (int k = 0; k < 8; ++k) wk[k] = w[(i + k) * 2 + h];
#pragma unroll
        for (int k = 0; k < 8; ++k)
            u[k] = *(const ushort4*)(Hpre + (size_t)s[k] * 256 + lane * 4);
#pragma unroll
        for (int k = 0; k < 8; ++k) {
            float4* a = (k & 3) == 0 ? &a0 : (k & 3) == 1 ? &a1 : (k & 3) == 2 ? &a2 : &a3;
            a->x += wk[k] * bf2f(u[k].x); a->y += wk[k] * bf2f(u[k].y);
            a->z += wk[k] * bf2f(u[k].z); a->w += wk[k] * bf2f(u[k].w);
        }
    }
    for (; i < re; ++i) {
        int s0 = csr_src[i];
        float w0 = w[i * 2 + h];
        ushort4 u0 = *(const ushort4*)(Hpre + (size_t)s0 * 256 + lane * 4);
        a0.x += w0 * bf2f(u0.x); a0.y += w0 * bf2f(u0.y);
        a0.z += w0 * bf2f(u0.z); a0.w += w0 * bf2f(u0.w);
    }
    float4 bv = ((const float4*)bias)[lane];
    float ox = (a0.x + a1.x + a2.x + a3.x) * rz + bv.x;
    float oy = (a0.y + a1.y + a2.y + a3.y) * rz + bv.y;
    float oz = (a0.z + a1.z + a2.z + a3.z) * rz + bv.z;
    float ow = (a0.w + a1.w + a2.w + a3.w) * rz + bv.w;
    ox = (ox > 0.f) ? ox : __expf(ox) - 1.f;
    oy = (oy > 0.f) ? oy : __expf(oy) - 1.f;
    oz = (oz > 0.f) ? oz : __expf(oz) - 1.f;
    ow = (ow > 0.f) ? ow : __expf(ow) - 1.f;
    ushort4 o;
    o.x = f2bf(ox); o.y = f2bf(oy); o.z = f2bf(oz); o.w = f2bf(ow);
    *(ushort4*)(out + (size_t)wid * 256 + lane * 4) = o;
}

// ------------------------- GAT aggregation, H=1 (fused softmax) -----------

__global__ void gat_agg_h1(const unsigned short* __restrict__ Hpre,
                           const float* __restrict__ es, const float* __restrict__ ed,
                           float* __restrict__ w,
                           const int* __restrict__ rowptr, const int* __restrict__ csr_src,
                           const float* __restrict__ bias, unsigned short* __restrict__ out,
                           int N) {
    int wid = (blockIdx.x * blockDim.x + threadIdx.x) >> 6;
    int lane = threadIdx.x & 63;
    if (wid >= N) return;
    const int rs = rowptr[wid], re = rowptr[wid + 1];
    const int half = lane >> 5, c = lane & 31;
    const float edn = ed[wid];

    float z = 0.f;
    for (int i = rs + lane; i < re; i += 64) {
        int s = csr_src[i];
        float e = es[s] + edn;
        e = (e > 0.f) ? e : 0.2f * e;
        float ww = __expf(e);
        z += ww;
        w[i] = ww;
    }
    z = wave_sum(z);
    const float rz = 1.f / (z + 1e-16f);
    __threadfence_block();  // drain vmcnt: same-wave RAW on w

    float4 a0 = {0.f, 0.f, 0.f, 0.f}, a1 = {0.f, 0.f, 0.f, 0.f};
    float4 a2 = {0.f, 0.f, 0.f, 0.f}, a3 = {0.f, 0.f, 0.f, 0.f};
    int i = rs + half;
    for (; i + 6 < re; i += 8) {
        int s0 = csr_src[i], s1 = csr_src[i + 2], s2 = csr_src[i + 4], s3 = csr_src[i + 6];
        float w0 = w[i], w1 = w[i + 2], w2 = w[i + 4], w3 = w[i + 6];
        ushort4 u0 = *(const ushort4*)(Hpre + (size_t)s0 * 128 + c * 4);
        ushort4 u1 = *(const ushort4*)(Hpre + (size_t)s1 * 128 + c * 4);
        ushort4 u2 = *(const ushort4*)(Hpre + (size_t)s2 * 128 + c * 4);
        ushort4 u3 = *(const ushort4*)(Hpre + (size_t)s3 * 128 + c * 4);
        a0.x += w0 * bf2f(u0.x); a0.y += w0 * bf2f(u0.y);
        a0.z += w0 * bf2f(u0.z); a0.w += w0 * bf2f(u0.w);
        a1.x += w1 * bf2f(u1.x); a1.y += w1 * bf2f(u1.y);
        a1.z += w1 * bf2f(u1.z); a1.w += w1 * bf2f(u1.w);
        a2.x += w2 * bf2f(u2.x); a2.y += w2 * bf2f(u2.y);
        a2.z += w2 * bf2f(u2.z); a2.w += w2 * bf2f(u2.w);
        a3.x += w3 * bf2f(u3.x); a3.y += w3 * bf2f(u3.y);
        a3.z += w3 * bf2f(u3.z); a3.w += w3 * bf2f(u3.w);
    }
    for (; i < re; i += 2) {
        int s0 = csr_src[i];
        float w0 = w[i];
        ushort4 u0 = *(const ushort4*)(Hpre + (size_t)s0 * 128 + c * 4);
        a0.x += w0 * bf2f(u0.x); a0.y += w0 * bf2f(u0.y);
        a0.z += w0 * bf2f(u0.z); a0.w += w0 * bf2f(u0.w);
    }
    float ox = a0.x + a1.x + a2.x + a3.x;
    float oy = a0.y + a1.y + a2.y + a3.y;
    float oz = a0.z + a1.z + a2.z + a3.z;
    float ow = a0.w + a1.w + a2.w + a3.w;
    ox += __shfl_xor(ox, 32, 64);
    oy += __shfl_xor(oy, 32, 64);
    oz += __shfl_xor(oz, 32, 64);
    ow += __shfl_xor(ow, 32, 64);
    if (lane < 32) {
        float4 bv = ((const float4*)bias)[c];
        ox = ox * rz + bv.x; oy = oy * rz + bv.y; oz = oz * rz + bv.z; ow = ow * rz + bv.w;
        ox = (ox > 0.f) ? ox : __expf(ox) - 1.f;
        oy = (oy > 0.f) ? oy : __expf(oy) - 1.f;
        oz = (oz > 0.f) ? oz : __expf(oz) - 1.f;
        ow = (ow > 0.f) ? ow : __expf(ow) - 1.f;
        ushort4 o;
        o.x = f2bf(ox); o.y = f2bf(oy); o.z = f2bf(oz); o.w = f2bf(ow);
        *(ushort4*)(out + (size_t)wid * 128 + c * 4) = o;
    }
}

// ------------------------- pool + heads (fused, done-counter) -------------

#define PCHUNK 256

__global__ __launch_bounds__(256) void pool_head(const unsigned short* __restrict__ h2,
                                                 const int* __restrict__ batch,
                                                 float* __restrict__ xsum,
                                                 const int* __restrict__ cnt,
                                                 int* __restrict__ done,
                                                 const float* __restrict__ Wp,
                                                 const float* __restrict__ bp,
                                                 const float* __restrict__ Wv,
                                                 const float* __restrict__ bv,
                                                 float* __restrict__ out, int N, int PB) {
    const int base = blockIdx.x * PCHUNK;
    const int rg = threadIdx.x >> 6;
    const int c2 = threadIdx.x & 63;
    float ax = 0.f, ay = 0.f;
    int gcur = -1;
    for (int r = rg; r < PCHUNK; r += 4) {
        int i = base + r;
        if (i >= N) break;
        int g = batch[i];
        if (g != gcur) {
            if (gcur >= 0) {
                atomicAdd(&xsum[gcur * 128 + c2 * 2 + 0], ax);
                atomicAdd(&xsum[gcur * 128 + c2 * 2 + 1], ay);
            }
            gcur = g; ax = 0.f; ay = 0.f;
        }
        ushort2 u = *(const ushort2*)(h2 + (size_t)i * 128 + c2 * 2);
        ax += bf2f(u.x); ay += bf2f(u.y);
    }
    if (gcur >= 0) {
        atomicAdd(&xsum[gcur * 128 + c2 * 2 + 0], ax);
        atomicAdd(&xsum[gcur * 128 + c2 * 2 + 1], ay);
    }

    // last block computes the heads
    __threadfence();
    __syncthreads();
    __shared__ int s_last;
    if (threadIdx.x == 0) s_last = (atomicAdd(done, 1) == PB - 1) ? 1 : 0;
    __syncthreads();
    if (!s_last) return;
    __threadfence();

    for (int o = threadIdx.x; o < 64 * 32; o += 256) {
        int g = o >> 5, a = o & 31;
        float inv = 1.f / fmaxf((float)cnt[g], 1.f);
        float acc = 0.f;
        for (int k = 0; k < 128; ++k) acc += xsum[g * 128 + k] * Wp[k * 32 + a];
        out[g * 32 + a] = acc * inv + bp[a];
    }
    if (threadIdx.x < 64) {
        int g = threadIdx.x;
        float inv = 1.f / fmaxf((float)cnt[g], 1.f);
        float acc = 0.f;
        for (int k = 0; k < 128; ++k) acc += xsum[g * 128 + k] * Wv[k];
        out[64 * 32 + g] = acc * inv + bv[0];
    }
}

// ---------------------------------------------------------------------------

extern "C" void kernel_launch(void* const* d_in, const int* in_sizes, int n_in,
                              void* d_out, int out_size, void* d_ws, size_t ws_size,
                              hipStream_t stream) {
    const float* x      = (const float*)d_in[0];
    const int*   ei     = (const int*)d_in[1];
    const int*   batch  = (const int*)d_in[2];
    const float* W1     = (const float*)d_in[3];
    const float* a_src1 = (const float*)d_in[4];
    const float* a_dst1 = (const float*)d_in[5];
    const float* b1     = (const float*)d_in[6];
    const float* W2     = (const float*)d_in[7];
    const float* a_src2 = (const float*)d_in[8];
    const float* a_dst2 = (const float*)d_in[9];
    const float* b2     = (const float*)d_in[10];
    const float* Wp     = (const float*)d_in[11];
    const float* bp     = (const float*)d_in[12];
    const float* Wv     = (const float*)d_in[13];
    const float* bv     = (const float*)d_in[14];

    const int N  = in_sizes[0] / 128;
    const int E  = in_sizes[1] / 2;
    const int ET = E + N;
    const int TILES = (N + 1023) / 1024;
    const int NPAD = ((N + 63) / 64) * 64;
    const int NBLK = NPAD / 64;
    const int PBLK = (N + PCHUNK - 1) / PCHUNK;

    char* ws = (char*)d_ws;
    size_t off = 0;
    auto alloc = [&](size_t bytes) -> void* {
        void* p = ws + off;
        off = (off + bytes + 255) & ~(size_t)255;
        return p;
    };
    unsigned short* h1pre = (unsigned short*)alloc((size_t)NPAD * 256 * 2);  // reused as h2pre
    unsigned short* h1bf  = (unsigned short*)alloc((size_t)NPAD * 256 * 2);
    unsigned short* h2bf  = (unsigned short*)alloc((size_t)N * 128 * 2);
    unsigned short* w1sw  = (unsigned short*)alloc((size_t)128 * 256 * 2);
    unsigned short* w2sw  = (unsigned short*)alloc((size_t)256 * 128 * 2);
    float* wbuf   = (float*)alloc((size_t)ET * 2 * 4);
    // contiguous zero region: deg | es1 | ed1 | es2 | ed2 | xsum | cnt | done
    const int ZINTS = 7 * N + 64 * 128 + 64 + 1;
    int*   zbase  = (int*)alloc(((size_t)ZINTS + 8) * 4);
    int*   deg    = zbase;
    float* es1    = (float*)(zbase + N);
    float* ed1    = es1 + 2 * N;
    float* es2    = ed1 + 2 * N;
    float* ed2    = es2 + N;
    float* xsum   = ed2 + N;
    int*   cnt    = (int*)(xsum + 64 * 128);
    int*   done   = cnt + 64;
    int*   rowptr = (int*)alloc((size_t)(N + 1) * 4);
    int*   cursor = (int*)alloc((size_t)N * 4);
    int*   csrsrc = (int*)alloc((size_t)ET * 4);
    int*   tsum   = (int*)alloc(64 * 4);
    unsigned short* h2pre = h1pre;  // h1pre dead after layer-1 agg
    const int zn4 = (ZINTS + 3) / 4;

    // --- zero everything at once (ws is poisoned every call) ---
    zero4_kernel<<<(zn4 + 255) / 256, 256, 0, stream>>>(zbase, zn4);

    // --- CSR build (separate launches; grid.sync costs ~180us/barrier) ---
    degree_kernel<<<(ET + 255) / 256, 256, 0, stream>>>(ei, batch, deg, cnt, E, N);
    scan_tiles<<<TILES, 256, 0, stream>>>(deg, tsum, N);
    scan_add<<<TILES, 256, 0, stream>>>(deg, tsum, rowptr, cursor, N, TILES);
    scatter_kernel<<<(ET + 255) / 256, 256, 0, stream>>>(ei, cursor, csrsrc, E, N);

    // --- weight swizzles (one launch) ---
    swizzle_both<<<32, 256, 0, stream>>>(W1, W2, w1sw, w2sw);

    // --- layer 1: heads=2 (A = fp32 x, cast in-reg; es1/ed1 fused) ---
    gemm_mfma<128, 256, 2, true><<<NBLK, 256, 0, stream>>>(x, w1sw, a_src1, a_dst1,
                                                           es1, ed1, h1pre, N);
    gat_agg_h2<<<(N + 3) / 4, 256, 0, stream>>>(h1pre, es1, ed1, wbuf, rowptr, csrsrc, b1,
                                                h1bf, N);

    // --- layer 2: heads=1 (es2/ed2 fused) ---
    gemm_mfma<256, 128, 1, false><<<NBLK, 256, 0, stream>>>(h1bf, w2sw, a_src2, a_dst2,
                                                            es2, ed2, h2pre, N);
    gat_agg_h1<<<(N + 3) / 4, 256, 0, stream>>>(h2pre, es2, ed2, wbuf, rowptr, csrsrc, b2,
                                                h2bf, N);

    // --- pool + heads (fused) ---
    pool_head<<<PBLK, 256, 0, stream>>>(h2bf, batch, xsum, cnt, done, Wp, bp, Wv, bv,
                                        (float*)d_out, N, PBLK);
}

// Round 10
// 426.482 us; speedup vs baseline: 2.5106x; 1.4167x over previous
//
#include <hip/hip_runtime.h>
#include <hip/hip_bf16.h>
#include <cstdint>

// ---------------------------------------------------------------------------
// GraphRLAgent: 2-layer GAT (heads=2 then 1) + global mean pool + 2 heads.
// Round 10: fix R9 regression — cnt histogram moved OUT of degree_kernel
// (50k same-address atomics on 64 counters = 220us serialization) back into
// pool_head as run-length flushes. Keeps pool+head fusion & h2 8-unroll.
// ---------------------------------------------------------------------------

typedef __attribute__((ext_vector_type(8))) short bf16x8;
typedef __attribute__((ext_vector_type(4))) float f32x4;

__device__ __forceinline__ float wave_sum(float v) {
#pragma unroll
    for (int off = 32; off >= 1; off >>= 1) v += __shfl_xor(v, off, 64);
    return v;
}

__device__ __forceinline__ unsigned short f2bf(float f) {
    union { float f; uint32_t u; } c; c.f = f;
    uint32_t u = c.u;
    return (unsigned short)((u + 0x7fffu + ((u >> 16) & 1u)) >> 16);
}

__device__ __forceinline__ float bf2f(unsigned short u) {
    union { uint32_t u; float f; } c; c.u = ((uint32_t)u) << 16;
    return c.f;
}

// ------------------------- zero (int4) ------------------------------------

__global__ void zero4_kernel(int* __restrict__ p, int n4) {
    int i = blockIdx.x * blockDim.x + threadIdx.x;
    if (i < n4) ((int4*)p)[i] = make_int4(0, 0, 0, 0);
}

// ------------------------- CSR construction -------------------------------

__global__ void degree_kernel(const int* __restrict__ ei, int* __restrict__ deg,
                              int E, int N) {
    int i = blockIdx.x * blockDim.x + threadIdx.x;
    if (i >= E + N) return;
    int dst = (i < E) ? ei[E + i] : (i - E);
    atomicAdd(&deg[dst], 1);
}

__global__ __launch_bounds__(256) void scan_tiles(int* __restrict__ deg,
                                                  int* __restrict__ tsum, int N) {
    __shared__ int buf[256];
    const int t = threadIdx.x;
    const int base = blockIdx.x * 1024 + t * 4;
    int v[4]; int s = 0;
#pragma unroll
    for (int k = 0; k < 4; ++k) { v[k] = (base + k < N) ? deg[base + k] : 0; s += v[k]; }
    buf[t] = s;
    __syncthreads();
#pragma unroll
    for (int off = 1; off < 256; off <<= 1) {
        int x = (t >= off) ? buf[t - off] : 0;
        __syncthreads();
        buf[t] += x;
        __syncthreads();
    }
    int run = buf[t] - s;
#pragma unroll
    for (int k = 0; k < 4; ++k) {
        if (base + k < N) deg[base + k] = run;
        run += v[k];
    }
    if (t == 255) tsum[blockIdx.x] = buf[255];
}

__global__ __launch_bounds__(256) void scan_add(const int* __restrict__ partial,
                                                const int* __restrict__ tsum,
                                                int* __restrict__ rowptr,
                                                int* __restrict__ cursor, int N, int T) {
    __shared__ int s_toff;
    const int tile = blockIdx.x;
    if (threadIdx.x < 64) {
        int t = threadIdx.x;
        int v = (t < T) ? tsum[t] : 0;
#pragma unroll
        for (int off = 1; off < 64; off <<= 1) {
            int x = __shfl_up(v, off, 64);
            if (t >= off) v += x;
        }
        int toff = (tile == 0) ? 0 : __shfl(v, tile - 1, 64);
        if (t == 0) s_toff = toff;
        if (tile == 0 && t == 63) rowptr[N] = v;
    }
    __syncthreads();
    const int toff = s_toff;
    int i = tile * 1024 + threadIdx.x * 4;
#pragma unroll
    for (int k = 0; k < 4; ++k) {
        if (i + k < N) {
            int r = partial[i + k] + toff;
            rowptr[i + k] = r;
            cursor[i + k] = r;
        }
    }
}

__global__ void scatter_kernel(const int* __restrict__ ei, int* __restrict__ cursor,
                               int* __restrict__ csr_src, int E, int N) {
    int i = blockIdx.x * blockDim.x + threadIdx.x;
    if (i >= E + N) return;
    int src, dst;
    if (i < E) { src = ei[i]; dst = ei[E + i]; }
    else       { src = dst = i - E; }
    int pos = atomicAdd(&cursor[dst], 1);
    csr_src[pos] = src;
}

// ------------------------- B swizzle (fp32 W -> frag-ordered bf16) --------

template <int K, int FOUT>
__device__ __forceinline__ void swizzle_body(const float* __restrict__ W,
                                             unsigned short* __restrict__ Bsw, int tid) {
    constexpr int CPW = FOUT / 4, NCT = CPW / 16, KST = K / 32;
    if (tid >= K * FOUT / 8) return;
    int lane = tid & 63;
    int rest = tid >> 6;
    int t = rest % KST; rest /= KST;
    int c = rest % NCT; rest /= NCT;
    int cg_ = rest;
    int quad = lane >> 4, lo = lane & 15;
    int col = cg_ * CPW + c * 16 + lo;
    unsigned short v[8];
#pragma unroll
    for (int j = 0; j < 8; ++j)
        v[j] = f2bf(W[(t * 32 + quad * 8 + j) * FOUT + col]);
    ushort4* dst = (ushort4*)(Bsw + (size_t)tid * 8);
    ushort4 o0, o1;
    o0.x = v[0]; o0.y = v[1]; o0.z = v[2]; o0.w = v[3];
    o1.x = v[4]; o1.y = v[5]; o1.z = v[6]; o1.w = v[7];
    dst[0] = o0; dst[1] = o1;
}

__global__ void swizzle_both(const float* __restrict__ W1, const float* __restrict__ W2,
                             unsigned short* __restrict__ B1, unsigned short* __restrict__ B2) {
    int b = blockIdx.x;
    if (b < 16) swizzle_body<128, 256>(W1, B1, b * 256 + threadIdx.x);
    else        swizzle_body<256, 128>(W2, B2, (b - 16) * 256 + threadIdx.x);
}

// ------------------------- bf16 MFMA GEMM + fused attn coef ---------------

template <int K, int FOUT, int H, bool A32>
__global__ __launch_bounds__(256) void gemm_mfma(const void* __restrict__ Av,
                                                 const unsigned short* __restrict__ Bsw,
                                                 const float* __restrict__ a_src,
                                                 const float* __restrict__ a_dst,
                                                 float* __restrict__ es, float* __restrict__ ed,
                                                 unsigned short* __restrict__ C, int N) {
    constexpr int CPW = FOUT / 4;
    constexpr int NCT = CPW / 16;
    constexpr int KST = K / 32;
    const int tid = threadIdx.x;
    const int wave = tid >> 6, lane = tid & 63;
    const int quad = lane >> 4, lo = lane & 15;
    const int n0 = blockIdx.x * 64;
    const int c0 = wave * CPW;

    bf16x8 bf[NCT][KST];
    {
        const bf16x8* Bp = (const bf16x8*)Bsw;
#pragma unroll
        for (int c = 0; c < NCT; ++c)
#pragma unroll
            for (int t = 0; t < KST; ++t)
                bf[c][t] = Bp[((wave * NCT + c) * KST + t) * 64 + lane];
    }

    f32x4 acc[4][NCT];
#pragma unroll
    for (int r = 0; r < 4; ++r)
#pragma unroll
        for (int c = 0; c < NCT; ++c) acc[r][c] = (f32x4){0.f, 0.f, 0.f, 0.f};

#pragma unroll
    for (int r = 0; r < 4; ++r) {
        const int arow = n0 + r * 16 + lo;
        if (A32) {
            const size_t rclamp = (arow < N) ? (size_t)arow : 0;
            const float* Ar = (const float*)Av + rclamp * K + quad * 8;
            const bool valid = arow < N;
#pragma unroll
            for (int t = 0; t < KST; ++t) {
                bf16x8 af;
                if (valid) {
                    float4 v0 = *(const float4*)(Ar + t * 32);
                    float4 v1 = *(const float4*)(Ar + t * 32 + 4);
                    af[0] = (short)f2bf(v0.x); af[1] = (short)f2bf(v0.y);
                    af[2] = (short)f2bf(v0.z); af[3] = (short)f2bf(v0.w);
                    af[4] = (short)f2bf(v1.x); af[5] = (short)f2bf(v1.y);
                    af[6] = (short)f2bf(v1.z); af[7] = (short)f2bf(v1.w);
                } else {
                    af = (bf16x8){0, 0, 0, 0, 0, 0, 0, 0};
                }
#pragma unroll
                for (int c = 0; c < NCT; ++c)
                    acc[r][c] = __builtin_amdgcn_mfma_f32_16x16x32_bf16(af, bf[c][t], acc[r][c],
                                                                       0, 0, 0);
            }
        } else {
            const unsigned short* Ar = (const unsigned short*)Av + (size_t)arow * K + quad * 8;
#pragma unroll
            for (int t = 0; t < KST; ++t) {
                bf16x8 af = *(const bf16x8*)(Ar + t * 32);
#pragma unroll
                for (int c = 0; c < NCT; ++c)
                    acc[r][c] = __builtin_amdgcn_mfma_f32_16x16x32_bf16(af, bf[c][t], acc[r][c],
                                                                       0, 0, 0);
            }
        }
    }

    // C/D layout: col = lane&15, row = quad*4 + j
#pragma unroll
    for (int r = 0; r < 4; ++r) {
        int row = n0 + r * 16 + quad * 4;
#pragma unroll
        for (int c = 0; c < NCT; ++c) {
            int col = c0 + c * 16 + lo;
#pragma unroll
            for (int j = 0; j < 4; ++j)
                if (row + j < N) C[(size_t)(row + j) * FOUT + col] = f2bf(acc[r][c][j]);
        }
    }

    // fused attention coefficients
    float asv[NCT], adv[NCT];
#pragma unroll
    for (int c = 0; c < NCT; ++c) {
        int col = c0 + c * 16 + lo;
        asv[c] = a_src[col];
        adv[c] = a_dst[col];
    }
    const int h = c0 / (FOUT / H);
#pragma unroll
    for (int r = 0; r < 4; ++r) {
#pragma unroll
        for (int j = 0; j < 4; ++j) {
            float ps = 0.f, pd = 0.f;
#pragma unroll
            for (int c = 0; c < NCT; ++c) { ps += acc[r][c][j] * asv[c]; pd += acc[r][c][j] * adv[c]; }
#pragma unroll
            for (int off = 1; off <= 8; off <<= 1) {
                ps += __shfl_xor(ps, off, 64);
                pd += __shfl_xor(pd, off, 64);
            }
            int row = n0 + r * 16 + quad * 4 + j;
            if (lo == 0 && row < N) {
                atomicAdd(&es[row * H + h], ps);
                atomicAdd(&ed[row * H + h], pd);
            }
        }
    }
}

// ------------------------- GAT aggregation, H=2 (fused softmax) -----------

__global__ void gat_agg_h2(const unsigned short* __restrict__ Hpre,
                           const float* __restrict__ es, const float* __restrict__ ed,
                           float* __restrict__ w,
                           const int* __restrict__ rowptr, const int* __restrict__ csr_src,
                           const float* __restrict__ bias, unsigned short* __restrict__ out,
                           int N) {
    int wid = (blockIdx.x * blockDim.x + threadIdx.x) >> 6;
    int lane = threadIdx.x & 63;
    if (wid >= N) return;
    const int rs = rowptr[wid], re = rowptr[wid + 1];
    const int h = lane >> 5;
    const float edn = ed[wid * 2 + h];

    float z = 0.f;
    for (int i = rs + (lane & 31); i < re; i += 32) {
        int s = csr_src[i];
        float e = es[s * 2 + h] + edn;
        e = (e > 0.f) ? e : 0.2f * e;
        float ww = __expf(e);
        z += ww;
        w[i * 2 + h] = ww;
    }
#pragma unroll
    for (int off = 16; off >= 1; off >>= 1) z += __shfl_xor(z, off, 64);
    const float rz = 1.f / (z + 1e-16f);
    __threadfence_block();  // drain vmcnt: same-wave RAW on w

    float4 a0 = {0.f, 0.f, 0.f, 0.f}, a1 = {0.f, 0.f, 0.f, 0.f};
    float4 a2 = {0.f, 0.f, 0.f, 0.f}, a3 = {0.f, 0.f, 0.f, 0.f};
    int i = rs;
    for (; i + 8 <= re; i += 8) {
        int s[8]; float wk[8]; ushort4 u[8];
#pragma unroll
        for (int k = 0; k < 8; ++k) s[k] = csr_src[i + k];
#pragma unroll
        for (int k = 0; k < 8; ++k) wk[k] = w[(i + k) * 2 + h];
#pragma unroll
        for (int k = 0; k < 8; ++k)
            u[k] = *(const ushort4*)(Hpre + (size_t)s[k] * 256 + lane * 4);
#pragma unroll
        for (int k = 0; k < 8; ++k) {
            float4* a = (k & 3) == 0 ? &a0 : (k & 3) == 1 ? &a1 : (k & 3) == 2 ? &a2 : &a3;
            a->x += wk[k] * bf2f(u[k].x); a->y += wk[k] * bf2f(u[k].y);
            a->z += wk[k] * bf2f(u[k].z); a->w += wk[k] * bf2f(u[k].w);
        }
    }
    for (; i < re; ++i) {
        int s0 = csr_src[i];
        float w0 = w[i * 2 + h];
        ushort4 u0 = *(const ushort4*)(Hpre + (size_t)s0 * 256 + lane * 4);
        a0.x += w0 * bf2f(u0.x); a0.y += w0 * bf2f(u0.y);
        a0.z += w0 * bf2f(u0.z); a0.w += w0 * bf2f(u0.w);
    }
    float4 bv = ((const float4*)bias)[lane];
    float ox = (a0.x + a1.x + a2.x + a3.x) * rz + bv.x;
    float oy = (a0.y + a1.y + a2.y + a3.y) * rz + bv.y;
    float oz = (a0.z + a1.z + a2.z + a3.z) * rz + bv.z;
    float ow = (a0.w + a1.w + a2.w + a3.w) * rz + bv.w;
    ox = (ox > 0.f) ? ox : __expf(ox) - 1.f;
    oy = (oy > 0.f) ? oy : __expf(oy) - 1.f;
    oz = (oz > 0.f) ? oz : __expf(oz) - 1.f;
    ow = (ow > 0.f) ? ow : __expf(ow) - 1.f;
    ushort4 o;
    o.x = f2bf(ox); o.y = f2bf(oy); o.z = f2bf(oz); o.w = f2bf(ow);
    *(ushort4*)(out + (size_t)wid * 256 + lane * 4) = o;
}

// ------------------------- GAT aggregation, H=1 (fused softmax) -----------

__global__ void gat_agg_h1(const unsigned short* __restrict__ Hpre,
                           const float* __restrict__ es, const float* __restrict__ ed,
                           float* __restrict__ w,
                           const int* __restrict__ rowptr, const int* __restrict__ csr_src,
                           const float* __restrict__ bias, unsigned short* __restrict__ out,
                           int N) {
    int wid = (blockIdx.x * blockDim.x + threadIdx.x) >> 6;
    int lane = threadIdx.x & 63;
    if (wid >= N) return;
    const int rs = rowptr[wid], re = rowptr[wid + 1];
    const int half = lane >> 5, c = lane & 31;
    const float edn = ed[wid];

    float z = 0.f;
    for (int i = rs + lane; i < re; i += 64) {
        int s = csr_src[i];
        float e = es[s] + edn;
        e = (e > 0.f) ? e : 0.2f * e;
        float ww = __expf(e);
        z += ww;
        w[i] = ww;
    }
    z = wave_sum(z);
    const float rz = 1.f / (z + 1e-16f);
    __threadfence_block();  // drain vmcnt: same-wave RAW on w

    float4 a0 = {0.f, 0.f, 0.f, 0.f}, a1 = {0.f, 0.f, 0.f, 0.f};
    float4 a2 = {0.f, 0.f, 0.f, 0.f}, a3 = {0.f, 0.f, 0.f, 0.f};
    int i = rs + half;
    for (; i + 6 < re; i += 8) {
        int s0 = csr_src[i], s1 = csr_src[i + 2], s2 = csr_src[i + 4], s3 = csr_src[i + 6];
        float w0 = w[i], w1 = w[i + 2], w2 = w[i + 4], w3 = w[i + 6];
        ushort4 u0 = *(const ushort4*)(Hpre + (size_t)s0 * 128 + c * 4);
        ushort4 u1 = *(const ushort4*)(Hpre + (size_t)s1 * 128 + c * 4);
        ushort4 u2 = *(const ushort4*)(Hpre + (size_t)s2 * 128 + c * 4);
        ushort4 u3 = *(const ushort4*)(Hpre + (size_t)s3 * 128 + c * 4);
        a0.x += w0 * bf2f(u0.x); a0.y += w0 * bf2f(u0.y);
        a0.z += w0 * bf2f(u0.z); a0.w += w0 * bf2f(u0.w);
        a1.x += w1 * bf2f(u1.x); a1.y += w1 * bf2f(u1.y);
        a1.z += w1 * bf2f(u1.z); a1.w += w1 * bf2f(u1.w);
        a2.x += w2 * bf2f(u2.x); a2.y += w2 * bf2f(u2.y);
        a2.z += w2 * bf2f(u2.z); a2.w += w2 * bf2f(u2.w);
        a3.x += w3 * bf2f(u3.x); a3.y += w3 * bf2f(u3.y);
        a3.z += w3 * bf2f(u3.z); a3.w += w3 * bf2f(u3.w);
    }
    for (; i < re; i += 2) {
        int s0 = csr_src[i];
        float w0 = w[i];
        ushort4 u0 = *(const ushort4*)(Hpre + (size_t)s0 * 128 + c * 4);
        a0.x += w0 * bf2f(u0.x); a0.y += w0 * bf2f(u0.y);
        a0.z += w0 * bf2f(u0.z); a0.w += w0 * bf2f(u0.w);
    }
    float ox = a0.x + a1.x + a2.x + a3.x;
    float oy = a0.y + a1.y + a2.y + a3.y;
    float oz = a0.z + a1.z + a2.z + a3.z;
    float ow = a0.w + a1.w + a2.w + a3.w;
    ox += __shfl_xor(ox, 32, 64);
    oy += __shfl_xor(oy, 32, 64);
    oz += __shfl_xor(oz, 32, 64);
    ow += __shfl_xor(ow, 32, 64);
    if (lane < 32) {
        float4 bv = ((const float4*)bias)[c];
        ox = ox * rz + bv.x; oy = oy * rz + bv.y; oz = oz * rz + bv.z; ow = ow * rz + bv.w;
        ox = (ox > 0.f) ? ox : __expf(ox) - 1.f;
        oy = (oy > 0.f) ? oy : __expf(oy) - 1.f;
        oz = (oz > 0.f) ? oz : __expf(oz) - 1.f;
        ow = (ow > 0.f) ? ow : __expf(ow) - 1.f;
        ushort4 o;
        o.x = f2bf(ox); o.y = f2bf(oy); o.z = f2bf(oz); o.w = f2bf(ow);
        *(ushort4*)(out + (size_t)wid * 128 + c * 4) = o;
    }
}

// ------------------------- pool + heads (fused, done-counter) -------------
// cnt accumulated here via run-length flushes (few atomics, low contention).

#define PCHUNK 256

__global__ __launch_bounds__(256) void pool_head(const unsigned short* __restrict__ h2,
                                                 const int* __restrict__ batch,
                                                 float* __restrict__ xsum,
                                                 int* __restrict__ cnt,
                                                 int* __restrict__ done,
                                                 const float* __restrict__ Wp,
                                                 const float* __restrict__ bp,
                                                 const float* __restrict__ Wv,
                                                 const float* __restrict__ bv,
                                                 float* __restrict__ out, int N, int PB) {
    const int base = blockIdx.x * PCHUNK;
    const int rg = threadIdx.x >> 6;
    const int c2 = threadIdx.x & 63;
    float ax = 0.f, ay = 0.f;
    int gcur = -1, run = 0;
    for (int r = rg; r < PCHUNK; r += 4) {
        int i = base + r;
        if (i >= N) break;
        int g = batch[i];
        if (g != gcur) {
            if (gcur >= 0) {
                atomicAdd(&xsum[gcur * 128 + c2 * 2 + 0], ax);
                atomicAdd(&xsum[gcur * 128 + c2 * 2 + 1], ay);
                if (c2 == 0) atomicAdd(&cnt[gcur], run);
            }
            gcur = g; ax = 0.f; ay = 0.f; run = 0;
        }
        ushort2 u = *(const ushort2*)(h2 + (size_t)i * 128 + c2 * 2);
        ax += bf2f(u.x); ay += bf2f(u.y);
        run += 1;
    }
    if (gcur >= 0) {
        atomicAdd(&xsum[gcur * 128 + c2 * 2 + 0], ax);
        atomicAdd(&xsum[gcur * 128 + c2 * 2 + 1], ay);
        if (c2 == 0) atomicAdd(&cnt[gcur], run);
    }

    // last block computes the heads
    __threadfence();
    __syncthreads();
    __shared__ int s_last;
    if (threadIdx.x == 0) s_last = (atomicAdd(done, 1) == PB - 1) ? 1 : 0;
    __syncthreads();
    if (!s_last) return;
    __threadfence();

    for (int o = threadIdx.x; o < 64 * 32; o += 256) {
        int g = o >> 5, a = o & 31;
        float inv = 1.f / fmaxf((float)cnt[g], 1.f);
        float acc = 0.f;
        for (int k = 0; k < 128; ++k) acc += xsum[g * 128 + k] * Wp[k * 32 + a];
        out[g * 32 + a] = acc * inv + bp[a];
    }
    if (threadIdx.x < 64) {
        int g = threadIdx.x;
        float inv = 1.f / fmaxf((float)cnt[g], 1.f);
        float acc = 0.f;
        for (int k = 0; k < 128; ++k) acc += xsum[g * 128 + k] * Wv[k];
        out[64 * 32 + g] = acc * inv + bv[0];
    }
}

// ---------------------------------------------------------------------------

extern "C" void kernel_launch(void* const* d_in, const int* in_sizes, int n_in,
                              void* d_out, int out_size, void* d_ws, size_t ws_size,
                              hipStream_t stream) {
    const float* x      = (const float*)d_in[0];
    const int*   ei     = (const int*)d_in[1];
    const int*   batch  = (const int*)d_in[2];
    const float* W1     = (const float*)d_in[3];
    const float* a_src1 = (const float*)d_in[4];
    const float* a_dst1 = (const float*)d_in[5];
    const float* b1     = (const float*)d_in[6];
    const float* W2     = (const float*)d_in[7];
    const float* a_src2 = (const float*)d_in[8];
    const float* a_dst2 = (const float*)d_in[9];
    const float* b2     = (const float*)d_in[10];
    const float* Wp     = (const float*)d_in[11];
    const float* bp     = (const float*)d_in[12];
    const float* Wv     = (const float*)d_in[13];
    const float* bv     = (const float*)d_in[14];

    const int N  = in_sizes[0] / 128;
    const int E  = in_sizes[1] / 2;
    const int ET = E + N;
    const int TILES = (N + 1023) / 1024;
    const int NPAD = ((N + 63) / 64) * 64;
    const int NBLK = NPAD / 64;
    const int PBLK = (N + PCHUNK - 1) / PCHUNK;

    char* ws = (char*)d_ws;
    size_t off = 0;
    auto alloc = [&](size_t bytes) -> void* {
        void* p = ws + off;
        off = (off + bytes + 255) & ~(size_t)255;
        return p;
    };
    unsigned short* h1pre = (unsigned short*)alloc((size_t)NPAD * 256 * 2);  // reused as h2pre
    unsigned short* h1bf  = (unsigned short*)alloc((size_t)NPAD * 256 * 2);
    unsigned short* h2bf  = (unsigned short*)alloc((size_t)N * 128 * 2);
    unsigned short* w1sw  = (unsigned short*)alloc((size_t)128 * 256 * 2);
    unsigned short* w2sw  = (unsigned short*)alloc((size_t)256 * 128 * 2);
    float* wbuf   = (float*)alloc((size_t)ET * 2 * 4);
    // contiguous zero region: deg | es1 | ed1 | es2 | ed2 | xsum | cnt | done
    const int ZINTS = 7 * N + 64 * 128 + 64 + 1;
    int*   zbase  = (int*)alloc(((size_t)ZINTS + 8) * 4);
    int*   deg    = zbase;
    float* es1    = (float*)(zbase + N);
    float* ed1    = es1 + 2 * N;
    float* es2    = ed1 + 2 * N;
    float* ed2    = es2 + N;
    float* xsum   = ed2 + N;
    int*   cnt    = (int*)(xsum + 64 * 128);
    int*   done   = cnt + 64;
    int*   rowptr = (int*)alloc((size_t)(N + 1) * 4);
    int*   cursor = (int*)alloc((size_t)N * 4);
    int*   csrsrc = (int*)alloc((size_t)ET * 4);
    int*   tsum   = (int*)alloc(64 * 4);
    unsigned short* h2pre = h1pre;  // h1pre dead after layer-1 agg
    const int zn4 = (ZINTS + 3) / 4;

    // --- zero everything at once (ws is poisoned every call) ---
    zero4_kernel<<<(zn4 + 255) / 256, 256, 0, stream>>>(zbase, zn4);

    // --- CSR build (separate launches; grid.sync costs ~180us/barrier) ---
    degree_kernel<<<(ET + 255) / 256, 256, 0, stream>>>(ei, deg, E, N);
    scan_tiles<<<TILES, 256, 0, stream>>>(deg, tsum, N);
    scan_add<<<TILES, 256, 0, stream>>>(deg, tsum, rowptr, cursor, N, TILES);
    scatter_kernel<<<(ET + 255) / 256, 256, 0, stream>>>(ei, cursor, csrsrc, E, N);

    // --- weight swizzles (one launch) ---
    swizzle_both<<<32, 256, 0, stream>>>(W1, W2, w1sw, w2sw);

    // --- layer 1: heads=2 (A = fp32 x, cast in-reg; es1/ed1 fused) ---
    gemm_mfma<128, 256, 2, true><<<NBLK, 256, 0, stream>>>(x, w1sw, a_src1, a_dst1,
                                                           es1, ed1, h1pre, N);
    gat_agg_h2<<<(N + 3) / 4, 256, 0, stream>>>(h1pre, es1, ed1, wbuf, rowptr, csrsrc, b1,
                                                h1bf, N);

    // --- layer 2: heads=1 (es2/ed2 fused) ---
    gemm_mfma<256, 128, 1, false><<<NBLK, 256, 0, stream>>>(h1bf, w2sw, a_src2, a_dst2,
                                                            es2, ed2, h2pre, N);
    gat_agg_h1<<<(N + 3) / 4, 256, 0, stream>>>(h2pre, es2, ed2, wbuf, rowptr, csrsrc, b2,
                                                h2bf, N);

    // --- pool + heads (fused) ---
    pool_head<<<PBLK, 256, 0, stream>>>(h2bf, batch, xsum, cnt, done, Wp, bp, Wv, bv,
                                        (float*)d_out, N, PBLK);
}

// Round 11
// 386.405 us; speedup vs baseline: 2.7710x; 1.1037x over previous
//
#include <hip/hip_runtime.h>
#include <hip/hip_bf16.h>
#include <cstdint>

// ---------------------------------------------------------------------------
// GraphRLAgent: 2-layer GAT (heads=2 then 1) + global mean pool + 2 heads.
// Round 11: SINGLE-PASS aggregation — softmax division commutes with the
// accumulation (out = (Σ w·h)/(Σ w)), so z and Σw·h are computed in one edge
// walk: no wbuf, no second csr_src pass, no fence. Pool/head reverted to the
// R7 split (one-block fused head was a 60us serial tail); h2 unroll back to
// explicit 4-deep (8-deep array form cost 4 VGPR + 10% occupancy).
// ---------------------------------------------------------------------------

typedef __attribute__((ext_vector_type(8))) short bf16x8;
typedef __attribute__((ext_vector_type(4))) float f32x4;

__device__ __forceinline__ float wave_sum(float v) {
#pragma unroll
    for (int off = 32; off >= 1; off >>= 1) v += __shfl_xor(v, off, 64);
    return v;
}

__device__ __forceinline__ unsigned short f2bf(float f) {
    union { float f; uint32_t u; } c; c.f = f;
    uint32_t u = c.u;
    return (unsigned short)((u + 0x7fffu + ((u >> 16) & 1u)) >> 16);
}

__device__ __forceinline__ float bf2f(unsigned short u) {
    union { uint32_t u; float f; } c; c.u = ((uint32_t)u) << 16;
    return c.f;
}

// ------------------------- zero (int4) ------------------------------------

__global__ void zero4_kernel(int* __restrict__ p, int n4) {
    int i = blockIdx.x * blockDim.x + threadIdx.x;
    if (i < n4) ((int4*)p)[i] = make_int4(0, 0, 0, 0);
}

// ------------------------- CSR construction -------------------------------

__global__ void degree_kernel(const int* __restrict__ ei, int* __restrict__ deg,
                              int E, int N) {
    int i = blockIdx.x * blockDim.x + threadIdx.x;
    if (i >= E + N) return;
    int dst = (i < E) ? ei[E + i] : (i - E);
    atomicAdd(&deg[dst], 1);
}

__global__ __launch_bounds__(256) void scan_tiles(int* __restrict__ deg,
                                                  int* __restrict__ tsum, int N) {
    __shared__ int buf[256];
    const int t = threadIdx.x;
    const int base = blockIdx.x * 1024 + t * 4;
    int v[4]; int s = 0;
#pragma unroll
    for (int k = 0; k < 4; ++k) { v[k] = (base + k < N) ? deg[base + k] : 0; s += v[k]; }
    buf[t] = s;
    __syncthreads();
#pragma unroll
    for (int off = 1; off < 256; off <<= 1) {
        int x = (t >= off) ? buf[t - off] : 0;
        __syncthreads();
        buf[t] += x;
        __syncthreads();
    }
    int run = buf[t] - s;
#pragma unroll
    for (int k = 0; k < 4; ++k) {
        if (base + k < N) deg[base + k] = run;
        run += v[k];
    }
    if (t == 255) tsum[blockIdx.x] = buf[255];
}

__global__ __launch_bounds__(256) void scan_add(const int* __restrict__ partial,
                                                const int* __restrict__ tsum,
                                                int* __restrict__ rowptr,
                                                int* __restrict__ cursor, int N, int T) {
    __shared__ int s_toff;
    const int tile = blockIdx.x;
    if (threadIdx.x < 64) {
        int t = threadIdx.x;
        int v = (t < T) ? tsum[t] : 0;
#pragma unroll
        for (int off = 1; off < 64; off <<= 1) {
            int x = __shfl_up(v, off, 64);
            if (t >= off) v += x;
        }
        int toff = (tile == 0) ? 0 : __shfl(v, tile - 1, 64);
        if (t == 0) s_toff = toff;
        if (tile == 0 && t == 63) rowptr[N] = v;
    }
    __syncthreads();
    const int toff = s_toff;
    int i = tile * 1024 + threadIdx.x * 4;
#pragma unroll
    for (int k = 0; k < 4; ++k) {
        if (i + k < N) {
            int r = partial[i + k] + toff;
            rowptr[i + k] = r;
            cursor[i + k] = r;
        }
    }
}

__global__ void scatter_kernel(const int* __restrict__ ei, int* __restrict__ cursor,
                               int* __restrict__ csr_src, int E, int N) {
    int i = blockIdx.x * blockDim.x + threadIdx.x;
    if (i >= E + N) return;
    int src, dst;
    if (i < E) { src = ei[i]; dst = ei[E + i]; }
    else       { src = dst = i - E; }
    int pos = atomicAdd(&cursor[dst], 1);
    csr_src[pos] = src;
}

// ------------------------- B swizzle (fp32 W -> frag-ordered bf16) --------

template <int K, int FOUT>
__device__ __forceinline__ void swizzle_body(const float* __restrict__ W,
                                             unsigned short* __restrict__ Bsw, int tid) {
    constexpr int CPW = FOUT / 4, NCT = CPW / 16, KST = K / 32;
    if (tid >= K * FOUT / 8) return;
    int lane = tid & 63;
    int rest = tid >> 6;
    int t = rest % KST; rest /= KST;
    int c = rest % NCT; rest /= NCT;
    int cg_ = rest;
    int quad = lane >> 4, lo = lane & 15;
    int col = cg_ * CPW + c * 16 + lo;
    unsigned short v[8];
#pragma unroll
    for (int j = 0; j < 8; ++j)
        v[j] = f2bf(W[(t * 32 + quad * 8 + j) * FOUT + col]);
    ushort4* dst = (ushort4*)(Bsw + (size_t)tid * 8);
    ushort4 o0, o1;
    o0.x = v[0]; o0.y = v[1]; o0.z = v[2]; o0.w = v[3];
    o1.x = v[4]; o1.y = v[5]; o1.z = v[6]; o1.w = v[7];
    dst[0] = o0; dst[1] = o1;
}

__global__ void swizzle_both(const float* __restrict__ W1, const float* __restrict__ W2,
                             unsigned short* __restrict__ B1, unsigned short* __restrict__ B2) {
    int b = blockIdx.x;
    if (b < 16) swizzle_body<128, 256>(W1, B1, b * 256 + threadIdx.x);
    else        swizzle_body<256, 128>(W2, B2, (b - 16) * 256 + threadIdx.x);
}

// ------------------------- bf16 MFMA GEMM + fused attn coef ---------------

template <int K, int FOUT, int H, bool A32>
__global__ __launch_bounds__(256) void gemm_mfma(const void* __restrict__ Av,
                                                 const unsigned short* __restrict__ Bsw,
                                                 const float* __restrict__ a_src,
                                                 const float* __restrict__ a_dst,
                                                 float* __restrict__ es, float* __restrict__ ed,
                                                 unsigned short* __restrict__ C, int N) {
    constexpr int CPW = FOUT / 4;
    constexpr int NCT = CPW / 16;
    constexpr int KST = K / 32;
    const int tid = threadIdx.x;
    const int wave = tid >> 6, lane = tid & 63;
    const int quad = lane >> 4, lo = lane & 15;
    const int n0 = blockIdx.x * 64;
    const int c0 = wave * CPW;

    bf16x8 bf[NCT][KST];
    {
        const bf16x8* Bp = (const bf16x8*)Bsw;
#pragma unroll
        for (int c = 0; c < NCT; ++c)
#pragma unroll
            for (int t = 0; t < KST; ++t)
                bf[c][t] = Bp[((wave * NCT + c) * KST + t) * 64 + lane];
    }

    f32x4 acc[4][NCT];
#pragma unroll
    for (int r = 0; r < 4; ++r)
#pragma unroll
        for (int c = 0; c < NCT; ++c) acc[r][c] = (f32x4){0.f, 0.f, 0.f, 0.f};

#pragma unroll
    for (int r = 0; r < 4; ++r) {
        const int arow = n0 + r * 16 + lo;
        if (A32) {
            const size_t rclamp = (arow < N) ? (size_t)arow : 0;
            const float* Ar = (const float*)Av + rclamp * K + quad * 8;
            const bool valid = arow < N;
#pragma unroll
            for (int t = 0; t < KST; ++t) {
                bf16x8 af;
                if (valid) {
                    float4 v0 = *(const float4*)(Ar + t * 32);
                    float4 v1 = *(const float4*)(Ar + t * 32 + 4);
                    af[0] = (short)f2bf(v0.x); af[1] = (short)f2bf(v0.y);
                    af[2] = (short)f2bf(v0.z); af[3] = (short)f2bf(v0.w);
                    af[4] = (short)f2bf(v1.x); af[5] = (short)f2bf(v1.y);
                    af[6] = (short)f2bf(v1.z); af[7] = (short)f2bf(v1.w);
                } else {
                    af = (bf16x8){0, 0, 0, 0, 0, 0, 0, 0};
                }
#pragma unroll
                for (int c = 0; c < NCT; ++c)
                    acc[r][c] = __builtin_amdgcn_mfma_f32_16x16x32_bf16(af, bf[c][t], acc[r][c],
                                                                       0, 0, 0);
            }
        } else {
            const unsigned short* Ar = (const unsigned short*)Av + (size_t)arow * K + quad * 8;
#pragma unroll
            for (int t = 0; t < KST; ++t) {
                bf16x8 af = *(const bf16x8*)(Ar + t * 32);
#pragma unroll
                for (int c = 0; c < NCT; ++c)
                    acc[r][c] = __builtin_amdgcn_mfma_f32_16x16x32_bf16(af, bf[c][t], acc[r][c],
                                                                       0, 0, 0);
            }
        }
    }

    // C/D layout: col = lane&15, row = quad*4 + j
#pragma unroll
    for (int r = 0; r < 4; ++r) {
        int row = n0 + r * 16 + quad * 4;
#pragma unroll
        for (int c = 0; c < NCT; ++c) {
            int col = c0 + c * 16 + lo;
#pragma unroll
            for (int j = 0; j < 4; ++j)
                if (row + j < N) C[(size_t)(row + j) * FOUT + col] = f2bf(acc[r][c][j]);
        }
    }

    // fused attention coefficients
    float asv[NCT], adv[NCT];
#pragma unroll
    for (int c = 0; c < NCT; ++c) {
        int col = c0 + c * 16 + lo;
        asv[c] = a_src[col];
        adv[c] = a_dst[col];
    }
    const int h = c0 / (FOUT / H);
#pragma unroll
    for (int r = 0; r < 4; ++r) {
#pragma unroll
        for (int j = 0; j < 4; ++j) {
            float ps = 0.f, pd = 0.f;
#pragma unroll
            for (int c = 0; c < NCT; ++c) { ps += acc[r][c][j] * asv[c]; pd += acc[r][c][j] * adv[c]; }
#pragma unroll
            for (int off = 1; off <= 8; off <<= 1) {
                ps += __shfl_xor(ps, off, 64);
                pd += __shfl_xor(pd, off, 64);
            }
            int row = n0 + r * 16 + quad * 4 + j;
            if (lo == 0 && row < N) {
                atomicAdd(&es[row * H + h], ps);
                atomicAdd(&ed[row * H + h], pd);
            }
        }
    }
}

// ------------------------- GAT aggregation, H=2 (single pass) -------------
// out = (Σ w_i·h_i)/(Σ w_i): z and the weighted sum accumulate in ONE edge
// walk. All lanes see every edge, so z needs no reduction. es is 400KB ->
// L2-resident broadcast loads.

__global__ void gat_agg_h2(const unsigned short* __restrict__ Hpre,
                           const float* __restrict__ es, const float* __restrict__ ed,
                           const int* __restrict__ rowptr, const int* __restrict__ csr_src,
                           const float* __restrict__ bias, unsigned short* __restrict__ out,
                           int N) {
    int wid = (blockIdx.x * blockDim.x + threadIdx.x) >> 6;
    int lane = threadIdx.x & 63;
    if (wid >= N) return;
    const int rs = rowptr[wid], re = rowptr[wid + 1];
    const int h = lane >> 5;
    const float edn = ed[wid * 2 + h];

    float z = 0.f;
    float4 a0 = {0.f, 0.f, 0.f, 0.f}, a1 = {0.f, 0.f, 0.f, 0.f};
    float4 a2 = {0.f, 0.f, 0.f, 0.f}, a3 = {0.f, 0.f, 0.f, 0.f};
    int i = rs;
    for (; i + 4 <= re; i += 4) {
        int s0 = csr_src[i], s1 = csr_src[i + 1], s2 = csr_src[i + 2], s3 = csr_src[i + 3];
        float e0 = es[s0 * 2 + h] + edn;
        float e1 = es[s1 * 2 + h] + edn;
        float e2 = es[s2 * 2 + h] + edn;
        float e3 = es[s3 * 2 + h] + edn;
        e0 = (e0 > 0.f) ? e0 : 0.2f * e0;
        e1 = (e1 > 0.f) ? e1 : 0.2f * e1;
        e2 = (e2 > 0.f) ? e2 : 0.2f * e2;
        e3 = (e3 > 0.f) ? e3 : 0.2f * e3;
        float w0 = __expf(e0), w1 = __expf(e1), w2 = __expf(e2), w3 = __expf(e3);
        z += (w0 + w1) + (w2 + w3);
        ushort4 u0 = *(const ushort4*)(Hpre + (size_t)s0 * 256 + lane * 4);
        ushort4 u1 = *(const ushort4*)(Hpre + (size_t)s1 * 256 + lane * 4);
        ushort4 u2 = *(const ushort4*)(Hpre + (size_t)s2 * 256 + lane * 4);
        ushort4 u3 = *(const ushort4*)(Hpre + (size_t)s3 * 256 + lane * 4);
        a0.x += w0 * bf2f(u0.x); a0.y += w0 * bf2f(u0.y);
        a0.z += w0 * bf2f(u0.z); a0.w += w0 * bf2f(u0.w);
        a1.x += w1 * bf2f(u1.x); a1.y += w1 * bf2f(u1.y);
        a1.z += w1 * bf2f(u1.z); a1.w += w1 * bf2f(u1.w);
        a2.x += w2 * bf2f(u2.x); a2.y += w2 * bf2f(u2.y);
        a2.z += w2 * bf2f(u2.z); a2.w += w2 * bf2f(u2.w);
        a3.x += w3 * bf2f(u3.x); a3.y += w3 * bf2f(u3.y);
        a3.z += w3 * bf2f(u3.z); a3.w += w3 * bf2f(u3.w);
    }
    for (; i < re; ++i) {
        int s0 = csr_src[i];
        float e0 = es[s0 * 2 + h] + edn;
        e0 = (e0 > 0.f) ? e0 : 0.2f * e0;
        float w0 = __expf(e0);
        z += w0;
        ushort4 u0 = *(const ushort4*)(Hpre + (size_t)s0 * 256 + lane * 4);
        a0.x += w0 * bf2f(u0.x); a0.y += w0 * bf2f(u0.y);
        a0.z += w0 * bf2f(u0.z); a0.w += w0 * bf2f(u0.w);
    }
    const float rz = 1.f / (z + 1e-16f);
    float4 bv = ((const float4*)bias)[lane];
    float ox = (a0.x + a1.x + a2.x + a3.x) * rz + bv.x;
    float oy = (a0.y + a1.y + a2.y + a3.y) * rz + bv.y;
    float oz = (a0.z + a1.z + a2.z + a3.z) * rz + bv.z;
    float ow = (a0.w + a1.w + a2.w + a3.w) * rz + bv.w;
    ox = (ox > 0.f) ? ox : __expf(ox) - 1.f;
    oy = (oy > 0.f) ? oy : __expf(oy) - 1.f;
    oz = (oz > 0.f) ? oz : __expf(oz) - 1.f;
    ow = (ow > 0.f) ? ow : __expf(ow) - 1.f;
    ushort4 o;
    o.x = f2bf(ox); o.y = f2bf(oy); o.z = f2bf(oz); o.w = f2bf(ow);
    *(ushort4*)(out + (size_t)wid * 256 + lane * 4) = o;
}

// ------------------------- GAT aggregation, H=1 (single pass) -------------
// Half-wave per edge (4 edges per half in flight); z summed per half then
// combined with one shfl_xor(32).

__global__ void gat_agg_h1(const unsigned short* __restrict__ Hpre,
                           const float* __restrict__ es, const float* __restrict__ ed,
                           const int* __restrict__ rowptr, const int* __restrict__ csr_src,
                           const float* __restrict__ bias, unsigned short* __restrict__ out,
                           int N) {
    int wid = (blockIdx.x * blockDim.x + threadIdx.x) >> 6;
    int lane = threadIdx.x & 63;
    if (wid >= N) return;
    const int rs = rowptr[wid], re = rowptr[wid + 1];
    const int half = lane >> 5, c = lane & 31;
    const float edn = ed[wid];

    float z = 0.f;
    float4 a0 = {0.f, 0.f, 0.f, 0.f}, a1 = {0.f, 0.f, 0.f, 0.f};
    float4 a2 = {0.f, 0.f, 0.f, 0.f}, a3 = {0.f, 0.f, 0.f, 0.f};
    int i = rs + half;
    for (; i + 6 < re; i += 8) {
        int s0 = csr_src[i], s1 = csr_src[i + 2], s2 = csr_src[i + 4], s3 = csr_src[i + 6];
        float e0 = es[s0] + edn, e1 = es[s1] + edn, e2 = es[s2] + edn, e3 = es[s3] + edn;
        e0 = (e0 > 0.f) ? e0 : 0.2f * e0;
        e1 = (e1 > 0.f) ? e1 : 0.2f * e1;
        e2 = (e2 > 0.f) ? e2 : 0.2f * e2;
        e3 = (e3 > 0.f) ? e3 : 0.2f * e3;
        float w0 = __expf(e0), w1 = __expf(e1), w2 = __expf(e2), w3 = __expf(e3);
        z += (w0 + w1) + (w2 + w3);
        ushort4 u0 = *(const ushort4*)(Hpre + (size_t)s0 * 128 + c * 4);
        ushort4 u1 = *(const ushort4*)(Hpre + (size_t)s1 * 128 + c * 4);
        ushort4 u2 = *(const ushort4*)(Hpre + (size_t)s2 * 128 + c * 4);
        ushort4 u3 = *(const ushort4*)(Hpre + (size_t)s3 * 128 + c * 4);
        a0.x += w0 * bf2f(u0.x); a0.y += w0 * bf2f(u0.y);
        a0.z += w0 * bf2f(u0.z); a0.w += w0 * bf2f(u0.w);
        a1.x += w1 * bf2f(u1.x); a1.y += w1 * bf2f(u1.y);
        a1.z += w1 * bf2f(u1.z); a1.w += w1 * bf2f(u1.w);
        a2.x += w2 * bf2f(u2.x); a2.y += w2 * bf2f(u2.y);
        a2.z += w2 * bf2f(u2.z); a2.w += w2 * bf2f(u2.w);
        a3.x += w3 * bf2f(u3.x); a3.y += w3 * bf2f(u3.y);
        a3.z += w3 * bf2f(u3.z); a3.w += w3 * bf2f(u3.w);
    }
    for (; i < re; i += 2) {
        int s0 = csr_src[i];
        float e0 = es[s0] + edn;
        e0 = (e0 > 0.f) ? e0 : 0.2f * e0;
        float w0 = __expf(e0);
        z += w0;
        ushort4 u0 = *(const ushort4*)(Hpre + (size_t)s0 * 128 + c * 4);
        a0.x += w0 * bf2f(u0.x); a0.y += w0 * bf2f(u0.y);
        a0.z += w0 * bf2f(u0.z); a0.w += w0 * bf2f(u0.w);
    }
    z += __shfl_xor(z, 32, 64);
    const float rz = 1.f / (z + 1e-16f);

    float ox = a0.x + a1.x + a2.x + a3.x;
    float oy = a0.y + a1.y + a2.y + a3.y;
    float oz = a0.z + a1.z + a2.z + a3.z;
    float ow = a0.w + a1.w + a2.w + a3.w;
    ox += __shfl_xor(ox, 32, 64);
    oy += __shfl_xor(oy, 32, 64);
    oz += __shfl_xor(oz, 32, 64);
    ow += __shfl_xor(ow, 32, 64);
    if (lane < 32) {
        float4 bv = ((const float4*)bias)[c];
        ox = ox * rz + bv.x; oy = oy * rz + bv.y; oz = oz * rz + bv.z; ow = ow * rz + bv.w;
        ox = (ox > 0.f) ? ox : __expf(ox) - 1.f;
        oy = (oy > 0.f) ? oy : __expf(oy) - 1.f;
        oz = (oz > 0.f) ? oz : __expf(oz) - 1.f;
        ow = (ow > 0.f) ? ow : __expf(ow) - 1.f;
        ushort4 o;
        o.x = f2bf(ox); o.y = f2bf(oy); o.z = f2bf(oz); o.w = f2bf(ow);
        *(ushort4*)(out + (size_t)wid * 128 + c * 4) = o;
    }
}

// ------------------------- global mean pool (chunk-parallel) --------------

#define PCHUNK 256

__global__ __launch_bounds__(256) void pool_partial(const unsigned short* __restrict__ h2,
                                                    const int* __restrict__ batch,
                                                    float* __restrict__ xsum,
                                                    int* __restrict__ cnt, int N) {
    const int base = blockIdx.x * PCHUNK;
    const int rg = threadIdx.x >> 6;
    const int c2 = threadIdx.x & 63;
    float ax = 0.f, ay = 0.f;
    int gcur = -1, run = 0;
    for (int r = rg; r < PCHUNK; r += 4) {
        int i = base + r;
        if (i >= N) break;
        int g = batch[i];
        if (g != gcur) {
            if (gcur >= 0) {
                atomicAdd(&xsum[gcur * 128 + c2 * 2 + 0], ax);
                atomicAdd(&xsum[gcur * 128 + c2 * 2 + 1], ay);
                if (c2 == 0) atomicAdd(&cnt[gcur], run);
            }
            gcur = g; ax = 0.f; ay = 0.f; run = 0;
        }
        ushort2 u = *(const ushort2*)(h2 + (size_t)i * 128 + c2 * 2);
        ax += bf2f(u.x); ay += bf2f(u.y);
        run += 1;
    }
    if (gcur >= 0) {
        atomicAdd(&xsum[gcur * 128 + c2 * 2 + 0], ax);
        atomicAdd(&xsum[gcur * 128 + c2 * 2 + 1], ay);
        if (c2 == 0) atomicAdd(&cnt[gcur], run);
    }
}

// ------------------------- policy / value heads ---------------------------

__global__ void head_kernel(const float* __restrict__ xsum, const int* __restrict__ cnt,
                            const float* __restrict__ Wp, const float* __restrict__ bp,
                            const float* __restrict__ Wv, const float* __restrict__ bv,
                            float* __restrict__ out) {
    int g = blockIdx.x, t = threadIdx.x;  // 64 threads
    __shared__ float p[128];
    float inv = 1.f / fmaxf((float)cnt[g], 1.f);
    p[t] = xsum[g * 128 + t] * inv;
    p[t + 64] = xsum[g * 128 + t + 64] * inv;
    __syncthreads();
    if (t < 32) {
        float acc = bp[t];
        for (int k = 0; k < 128; ++k) acc += p[k] * Wp[k * 32 + t];
        out[g * 32 + t] = acc;
    } else if (t == 32) {
        float acc = bv[0];
        for (int k = 0; k < 128; ++k) acc += p[k] * Wv[k];
        out[64 * 32 + g] = acc;
    }
}

// ---------------------------------------------------------------------------

extern "C" void kernel_launch(void* const* d_in, const int* in_sizes, int n_in,
                              void* d_out, int out_size, void* d_ws, size_t ws_size,
                              hipStream_t stream) {
    const float* x      = (const float*)d_in[0];
    const int*   ei     = (const int*)d_in[1];
    const int*   batch  = (const int*)d_in[2];
    const float* W1     = (const float*)d_in[3];
    const float* a_src1 = (const float*)d_in[4];
    const float* a_dst1 = (const float*)d_in[5];
    const float* b1     = (const float*)d_in[6];
    const float* W2     = (const float*)d_in[7];
    const float* a_src2 = (const float*)d_in[8];
    const float* a_dst2 = (const float*)d_in[9];
    const float* b2     = (const float*)d_in[10];
    const float* Wp     = (const float*)d_in[11];
    const float* bp     = (const float*)d_in[12];
    const float* Wv     = (const float*)d_in[13];
    const float* bv     = (const float*)d_in[14];

    const int N  = in_sizes[0] / 128;
    const int E  = in_sizes[1] / 2;
    const int ET = E + N;
    const int TILES = (N + 1023) / 1024;
    const int NPAD = ((N + 63) / 64) * 64;
    const int NBLK = NPAD / 64;
    const int PBLK = (N + PCHUNK - 1) / PCHUNK;

    char* ws = (char*)d_ws;
    size_t off = 0;
    auto alloc = [&](size_t bytes) -> void* {
        void* p = ws + off;
        off = (off + bytes + 255) & ~(size_t)255;
        return p;
    };
    unsigned short* h1pre = (unsigned short*)alloc((size_t)NPAD * 256 * 2);  // reused as h2pre
    unsigned short* h1bf  = (unsigned short*)alloc((size_t)NPAD * 256 * 2);
    unsigned short* h2bf  = (unsigned short*)alloc((size_t)N * 128 * 2);
    unsigned short* w1sw  = (unsigned short*)alloc((size_t)128 * 256 * 2);
    unsigned short* w2sw  = (unsigned short*)alloc((size_t)256 * 128 * 2);
    // contiguous zero region: deg | es1 | ed1 | es2 | ed2 | xsum | cnt
    const int ZINTS = 7 * N + 64 * 128 + 64;
    int*   zbase  = (int*)alloc(((size_t)ZINTS + 8) * 4);
    int*   deg    = zbase;
    float* es1    = (float*)(zbase + N);
    float* ed1    = es1 + 2 * N;
    float* es2    = ed1 + 2 * N;
    float* ed2    = es2 + N;
    float* xsum   = ed2 + N;
    int*   cnt    = (int*)(xsum + 64 * 128);
    int*   rowptr = (int*)alloc((size_t)(N + 1) * 4);
    int*   cursor = (int*)alloc((size_t)N * 4);
    int*   csrsrc = (int*)alloc((size_t)ET * 4);
    int*   tsum   = (int*)alloc(64 * 4);
    unsigned short* h2pre = h1pre;  // h1pre dead after layer-1 agg
    const int zn4 = (ZINTS + 3) / 4;

    // --- zero everything at once (ws is poisoned every call) ---
    zero4_kernel<<<(zn4 + 255) / 256, 256, 0, stream>>>(zbase, zn4);

    // --- CSR build ---
    degree_kernel<<<(ET + 255) / 256, 256, 0, stream>>>(ei, deg, E, N);
    scan_tiles<<<TILES, 256, 0, stream>>>(deg, tsum, N);
    scan_add<<<TILES, 256, 0, stream>>>(deg, tsum, rowptr, cursor, N, TILES);
    scatter_kernel<<<(ET + 255) / 256, 256, 0, stream>>>(ei, cursor, csrsrc, E, N);

    // --- weight swizzles (one launch) ---
    swizzle_both<<<32, 256, 0, stream>>>(W1, W2, w1sw, w2sw);

    // --- layer 1: heads=2 (A = fp32 x, cast in-reg; es1/ed1 fused) ---
    gemm_mfma<128, 256, 2, true><<<NBLK, 256, 0, stream>>>(x, w1sw, a_src1, a_dst1,
                                                           es1, ed1, h1pre, N);
    gat_agg_h2<<<(N + 3) / 4, 256, 0, stream>>>(h1pre, es1, ed1, rowptr, csrsrc, b1,
                                                h1bf, N);

    // --- layer 2: heads=1 (es2/ed2 fused) ---
    gemm_mfma<256, 128, 1, false><<<NBLK, 256, 0, stream>>>(h1bf, w2sw, a_src2, a_dst2,
                                                            es2, ed2, h2pre, N);
    gat_agg_h1<<<(N + 3) / 4, 256, 0, stream>>>(h2pre, es2, ed2, rowptr, csrsrc, b2,
                                                h2bf, N);

    // --- pool + heads ---
    pool_partial<<<PBLK, 256, 0, stream>>>(h2bf, batch, xsum, cnt, N);
    head_kernel<<<64, 64, 0, stream>>>(xsum, cnt, Wp, bp, Wv, bv, (float*)d_out);
}